// Round 1
// baseline (1029.796 us; speedup 1.0000x reference)
//
#include <hip/hip_runtime.h>
#include <hip/hip_bf16.h>

// Shapes (fixed): B=4, SEQ=1024, C=256, H=4, Dk=64, L=4096, N_TOP=SAMPLE_K=36
#define BHn 16      // B*H
#define Ln 4096
#define DKn 64
#define NTOP 36
#define SKn 36

// ---------------- GEMM: C = A(16384x256) @ W(256x256) + bias ----------------
// gather!=0: A is the virtual permuted x built from s0..s3 (et, co, mp, vol)
__global__ __launch_bounds__(256) void gemm_bias(
    const float* __restrict__ A, const float* __restrict__ W,
    const float* __restrict__ bias, float* __restrict__ Cout,
    const float* __restrict__ s0, const float* __restrict__ s1,
    const float* __restrict__ s2, const float* __restrict__ s3,
    int gather) {
  __shared__ float As[16][64];
  __shared__ float Bs[16][64];
  int tid = threadIdx.x;
  int tx = tid & 15, ty = tid >> 4;
  int row0 = blockIdx.y * 64, col0 = blockIdx.x * 64;
  float acc[4][4] = {};
  for (int k0 = 0; k0 < 256; k0 += 16) {
    // A tile: 64 rows x 16 k
    for (int i = tid; i < 1024; i += 256) {
      int r = i >> 4, kk = i & 15;
      int row = row0 + r;
      float a;
      if (gather) {
        int l = row & 4095, b = row >> 12, c = k0 + kk;
        int part = (l >> 2) & 3;
        int seq = ((l >> 4) << 2) | (l & 3);
        const float* sp = (part == 0) ? s0 : (part == 1) ? s1 : (part == 2) ? s2 : s3;
        a = sp[(size_t)((b << 10) + seq) * 256 + c];
      } else {
        a = A[(size_t)row * 256 + k0 + kk];
      }
      As[kk][r] = a;
    }
    // B tile: 16 k x 64 cols
    for (int i = tid; i < 1024; i += 256) {
      int kk = i >> 6, c = i & 63;
      Bs[kk][c] = W[(size_t)(k0 + kk) * 256 + col0 + c];
    }
    __syncthreads();
#pragma unroll
    for (int kk = 0; kk < 16; ++kk) {
      float av[4], bv[4];
#pragma unroll
      for (int i = 0; i < 4; ++i) av[i] = As[kk][ty * 4 + i];
#pragma unroll
      for (int j = 0; j < 4; ++j) bv[j] = Bs[kk][tx * 4 + j];
#pragma unroll
      for (int i = 0; i < 4; ++i)
#pragma unroll
        for (int j = 0; j < 4; ++j) acc[i][j] += av[i] * bv[j];
    }
    __syncthreads();
  }
#pragma unroll
  for (int i = 0; i < 4; ++i) {
    int r = row0 + ty * 4 + i;
#pragma unroll
    for (int j = 0; j < 4; ++j) {
      int c = col0 + tx * 4 + j;
      Cout[(size_t)r * 256 + c] = acc[i][j] + bias[c];
    }
  }
}

// ------------- sampled QK^T and M = max - sum/L, one wave per (b,h,s) -------
__global__ __launch_bounds__(256) void qks_m(
    const float* __restrict__ q, const float* __restrict__ k,
    const int* __restrict__ idxs, float* __restrict__ Mout) {
  int wave = threadIdx.x >> 6;
  int lane = threadIdx.x & 63;
  int g = blockIdx.x * 4 + wave;   // 0..65535 : bh*4096 + s
  int bh = g >> 12;
  int s = g & 4095;
  float qd = q[(size_t)g * 64 + lane];
  const int* irow = idxs + s * SKn;
  float mx = -INFINITY, sm = 0.f;
  for (int j = 0; j < SKn; ++j) {
    int is = irow[j];
    float p = qd * k[((size_t)((bh << 12) | is)) * 64 + lane];
#pragma unroll
    for (int m2 = 1; m2 < 64; m2 <<= 1) p += __shfl_xor(p, m2, 64);
    mx = fmaxf(mx, p);
    sm += p;
  }
  if (lane == 0) Mout[g] = mx - sm * (1.0f / 4096.0f);
}

// ------------- top-36 per (b,h): repeated block argmax ----------------------
__global__ __launch_bounds__(256) void topk_kernel(
    const float* __restrict__ M, int* __restrict__ topidx) {
  __shared__ float sv[4096];
  __shared__ float rv[256];
  __shared__ int ri[256];
  int bh = blockIdx.x;
  int t = threadIdx.x;
  for (int i = t; i < 4096; i += 256) sv[i] = M[(size_t)bh * 4096 + i];
  __syncthreads();
  for (int u = 0; u < NTOP; ++u) {
    float best = -INFINITY; int bi = 0x7fffffff;
    for (int i = t; i < 4096; i += 256) {
      float v = sv[i];
      if (v > best || (v == best && i < bi)) { best = v; bi = i; }
    }
    rv[t] = best; ri[t] = bi;
    __syncthreads();
    for (int s2 = 128; s2 > 0; s2 >>= 1) {
      if (t < s2) {
        if (rv[t + s2] > rv[t] || (rv[t + s2] == rv[t] && ri[t + s2] < ri[t])) {
          rv[t] = rv[t + s2]; ri[t] = ri[t + s2];
        }
      }
      __syncthreads();
    }
    if (t == 0) { topidx[bh * NTOP + u] = ri[0]; sv[ri[0]] = -INFINITY; }
    __syncthreads();
  }
}

// ------------- v row-sum per (b,h) ------------------------------------------
__global__ __launch_bounds__(64) void vsum_partial(
    const float* __restrict__ v, float* __restrict__ part) {
  int bh = blockIdx.x, ch = blockIdx.y;
  int lane = threadIdx.x;
  float acc = 0.f;
  for (int l = ch * 256; l < ch * 256 + 256; ++l)
    acc += v[((size_t)bh * 4096 + l) * 64 + lane];
  part[((size_t)bh * 16 + ch) * 64 + lane] = acc;
}

__global__ __launch_bounds__(64) void vsum_final(
    const float* __restrict__ part, float* __restrict__ vsum) {
  int bh = blockIdx.x, lane = threadIdx.x;
  float acc = 0.f;
  for (int ch = 0; ch < 16; ++ch) acc += part[((size_t)bh * 16 + ch) * 64 + lane];
  vsum[bh * 64 + lane] = acc;
}

// ------------- full attention for the 36 selected rows per (b,h) ------------
__global__ __launch_bounds__(256) void attn_kernel(
    const float* __restrict__ q, const float* __restrict__ k,
    const float* __restrict__ v, const int* __restrict__ topidx,
    float* __restrict__ upd) {
  __shared__ float4 qs4[16];
  __shared__ float sc[4096];
  __shared__ float red[256];
  int bh = blockIdx.x / NTOP;
  int u = blockIdx.x % NTOP;
  int t = threadIdx.x;
  int m = topidx[bh * NTOP + u];
  size_t base = (size_t)bh * 4096;
  float* qsf = (float*)qs4;
  if (t < 64) qsf[t] = q[(base + m) * 64 + t];
  __syncthreads();
  for (int l = t; l < 4096; l += 256) {
    const float4* kr = (const float4*)(k + (base + l) * 64);
    float acc = 0.f;
#pragma unroll
    for (int d4 = 0; d4 < 16; ++d4) {
      float4 kv = kr[d4];
      float4 qv = qs4[d4];
      acc += kv.x * qv.x + kv.y * qv.y + kv.z * qv.z + kv.w * qv.w;
    }
    sc[l] = acc * 0.125f;   // 1/sqrt(64)
  }
  __syncthreads();
  float mx = -INFINITY;
  for (int l = t; l < 4096; l += 256) mx = fmaxf(mx, sc[l]);
  red[t] = mx; __syncthreads();
  for (int s2 = 128; s2 > 0; s2 >>= 1) {
    if (t < s2) red[t] = fmaxf(red[t], red[t + s2]);
    __syncthreads();
  }
  mx = red[0]; __syncthreads();
  float sm = 0.f;
  for (int l = t; l < 4096; l += 256) { float e = expf(sc[l] - mx); sc[l] = e; sm += e; }
  red[t] = sm; __syncthreads();
  for (int s2 = 128; s2 > 0; s2 >>= 1) {
    if (t < s2) red[t] += red[t + s2];
    __syncthreads();
  }
  float denom = red[0];
  __syncthreads();
  int d = t & 63, lq = t >> 6;
  float acc = 0.f;
  for (int l = lq; l < 4096; l += 4) acc += sc[l] * v[(base + l) * 64 + d];
  red[t] = acc; __syncthreads();
  if (lq == 0) {
    float tot = red[d] + red[64 + d] + red[128 + d] + red[192 + d];
    upd[((size_t)bh * NTOP + u) * 64 + d] = tot / denom;
  }
}

// ------------- ctx = broadcast(vsum), then scatter upd ----------------------
__global__ __launch_bounds__(256) void ctx_fill(
    const float* __restrict__ vsum, float4* __restrict__ ctx4) {
  int i = blockIdx.x * 256 + threadIdx.x;  // over 1,048,576 float4s
  int d4 = i & 15;
  int bh = i >> 16;
  ctx4[i] = ((const float4*)vsum)[bh * 16 + d4];
}

__global__ __launch_bounds__(64) void ctx_scatter(
    const float* __restrict__ upd, const int* __restrict__ topidx,
    float* __restrict__ ctx) {
  int bh = blockIdx.x / NTOP, u = blockIdx.x % NTOP;
  int m = topidx[bh * NTOP + u];
  ctx[((size_t)bh * 4096 + m) * 64 + threadIdx.x] =
      upd[((size_t)bh * NTOP + u) * 64 + threadIdx.x];
}

extern "C" void kernel_launch(void* const* d_in, const int* in_sizes, int n_in,
                              void* d_out, int out_size, void* d_ws, size_t ws_size,
                              hipStream_t stream) {
  const float* et  = (const float*)d_in[0];
  const float* mp  = (const float*)d_in[1];
  const float* co  = (const float*)d_in[2];
  const float* vol = (const float*)d_in[3];
  const float* Wq = (const float*)d_in[4];
  const float* bq = (const float*)d_in[5];
  const float* Wk = (const float*)d_in[6];
  const float* bk = (const float*)d_in[7];
  const float* Wv = (const float*)d_in[8];
  const float* bv = (const float*)d_in[9];
  const float* Wo = (const float*)d_in[10];
  const float* bo = (const float*)d_in[11];
  const int* idxs = (const int*)d_in[12];
  float* out = (float*)d_out;

  char* ws = (char*)d_ws;
  const size_t BIG = 16u * 1024u * 1024u;  // 16 MB per (B,H,L,Dk) f32 buffer
  float* qb  = (float*)(ws);               // also reused as ctx afterwards
  float* kb  = (float*)(ws + BIG);
  float* vb  = (float*)(ws + 2 * BIG);
  char*  sm  = ws + 3 * BIG;
  float* Mbuf   = (float*)(sm);                       // 65536 * 4 = 256 KB
  int*   topidx = (int*)(sm + 262144);                // 2304 B (pad 4 KB)
  float* vpart  = (float*)(sm + 262144 + 4096);       // 64 KB
  float* vsum   = (float*)(sm + 262144 + 4096 + 65536);        // 4 KB
  float* updb   = (float*)(sm + 262144 + 4096 + 65536 + 4096); // 144 KB

  dim3 ggrid(4, 256);  // N/64, M/64

  // QKV projections with fused input-permutation gather (x never materialized)
  gemm_bias<<<ggrid, 256, 0, stream>>>(nullptr, Wq, bq, qb, et, co, mp, vol, 1);
  gemm_bias<<<ggrid, 256, 0, stream>>>(nullptr, Wk, bk, kb, et, co, mp, vol, 1);
  gemm_bias<<<ggrid, 256, 0, stream>>>(nullptr, Wv, bv, vb, et, co, mp, vol, 1);

  // Sampled scores -> sparsity measure M
  qks_m<<<16384, 256, 0, stream>>>(qb, kb, idxs, Mbuf);

  // top-36 per (b,h)
  topk_kernel<<<BHn, 256, 0, stream>>>(Mbuf, topidx);

  // v column sums
  vsum_partial<<<dim3(BHn, 16), 64, 0, stream>>>(vb, vpart);
  vsum_final<<<BHn, 64, 0, stream>>>(vpart, vsum);

  // dense attention for selected rows
  attn_kernel<<<BHn * NTOP, 256, 0, stream>>>(qb, kb, vb, topidx, updb);

  // ctx: broadcast vsum, overwrite selected rows; reuse qb's buffer (q is dead
  // only after attn_kernel -> ctx built afterwards, stream-ordered)
  ctx_fill<<<4096, 256, 0, stream>>>(vsum, (float4*)qb);
  ctx_scatter<<<BHn * NTOP, 64, 0, stream>>>(updb, topidx, qb);

  // output projection
  gemm_bias<<<ggrid, 256, 0, stream>>>(qb, Wo, bo, out, nullptr, nullptr, nullptr, nullptr, 0);
}

// Round 2
// 428.719 us; speedup vs baseline: 2.4020x; 2.4020x over previous
//
#include <hip/hip_runtime.h>
#include <hip/hip_bf16.h>

// Shapes (fixed): B=4, SEQ=1024, C=256, H=4, Dk=64, L=4096, N_TOP=SAMPLE_K=36
#define BHn 16
#define Ln 4096
#define NTOP 36
#define SKn 36
#define NCHUNK 64   // l-chunks of 64 for attn partials

// ---------------- GEMM: O = A(16384x256) @ W(256x256) + bias ----------------
// 128x128 tile, 256 threads, 8x8 micro-tile. Up to 3 (W,bias,O) triples
// selected by blockIdx.x>>1 (fused QKV). gather!=0: A is the virtual permuted
// x built from s0..s3 (et, co, mp, vol order).
__global__ __launch_bounds__(256) void gemm128(
    const float* __restrict__ A,
    const float* __restrict__ W0, const float* __restrict__ W1, const float* __restrict__ W2,
    const float* __restrict__ b0, const float* __restrict__ b1, const float* __restrict__ b2,
    float* __restrict__ o0, float* __restrict__ o1, float* __restrict__ o2,
    const float* __restrict__ s0, const float* __restrict__ s1,
    const float* __restrict__ s2, const float* __restrict__ s3,
    int gather) {
  __shared__ float As[16][136];  // [k][row], padded
  __shared__ float Bs[16][132];  // [k][col], padded
  int t = threadIdx.x;
  int w = blockIdx.x >> 1;
  int col0 = (blockIdx.x & 1) * 128;
  int row0 = blockIdx.y * 128;
  const float* W = (w == 0) ? W0 : (w == 1) ? W1 : W2;
  const float* bias = (w == 0) ? b0 : (w == 1) ? b1 : b2;
  float* O = (w == 0) ? o0 : (w == 1) ? o1 : o2;
  int tx = t & 15, ty = t >> 4;

  // A-load assignment: row = t>>1, 8 k's starting at (t&1)*8
  int arow = row0 + (t >> 1);
  int kh = (t & 1) * 8;
  const float* abase;
  if (gather) {
    int l = arow & 4095, b = arow >> 12;
    int part = (l >> 2) & 3;
    int seq = ((l >> 4) << 2) | (l & 3);
    const float* sp = (part == 0) ? s0 : (part == 1) ? s1 : (part == 2) ? s2 : s3;
    abase = sp + (size_t)((b << 10) + seq) * 256;
  } else {
    abase = A + (size_t)arow * 256;
  }
  // B-load assignment: kk = t>>4, 8 cols starting at tx*8
  int kk = t >> 4;

  float acc[8][8] = {};
  for (int k0 = 0; k0 < 256; k0 += 16) {
    float4 a0 = ((const float4*)(abase + k0 + kh))[0];
    float4 a1 = ((const float4*)(abase + k0 + kh))[1];
    int r = t >> 1;
    As[kh + 0][r] = a0.x; As[kh + 1][r] = a0.y; As[kh + 2][r] = a0.z; As[kh + 3][r] = a0.w;
    As[kh + 4][r] = a1.x; As[kh + 5][r] = a1.y; As[kh + 6][r] = a1.z; As[kh + 7][r] = a1.w;
    const float* wrow = W + (size_t)(k0 + kk) * 256 + col0 + tx * 8;
    float4 bb0 = ((const float4*)wrow)[0];
    float4 bb1 = ((const float4*)wrow)[1];
    *((float4*)&Bs[kk][tx * 8]) = bb0;
    *((float4*)&Bs[kk][tx * 8 + 4]) = bb1;
    __syncthreads();
#pragma unroll
    for (int k2 = 0; k2 < 16; ++k2) {
      float av[8], bv[8];
      *(float4*)&av[0] = *(const float4*)&As[k2][ty * 8];
      *(float4*)&av[4] = *(const float4*)&As[k2][ty * 8 + 4];
      *(float4*)&bv[0] = *(const float4*)&Bs[k2][tx * 8];
      *(float4*)&bv[4] = *(const float4*)&Bs[k2][tx * 8 + 4];
#pragma unroll
      for (int i = 0; i < 8; ++i)
#pragma unroll
        for (int j = 0; j < 8; ++j) acc[i][j] += av[i] * bv[j];
    }
    __syncthreads();
  }
#pragma unroll
  for (int i = 0; i < 8; ++i) {
    int row = row0 + ty * 8 + i;
    float* orow = O + (size_t)row * 256 + col0 + tx * 8;
#pragma unroll
    for (int j = 0; j < 8; ++j) acc[i][j] += bias[col0 + tx * 8 + j];
    ((float4*)orow)[0] = *(float4*)&acc[i][0];
    ((float4*)orow)[1] = *(float4*)&acc[i][4];
  }
}

// ------------- sampled QK^T and M = max - sum/L, one wave per (b,h,s) -------
__global__ __launch_bounds__(256) void qks_m(
    const float* __restrict__ q, const float* __restrict__ k,
    const int* __restrict__ idxs, float* __restrict__ Mout) {
  int wave = threadIdx.x >> 6;
  int lane = threadIdx.x & 63;
  int g = blockIdx.x * 4 + wave;   // bh*4096 + s
  int bh = g >> 12;
  int s = g & 4095;
  float qd = q[(size_t)g * 64 + lane];
  const int* irow = idxs + s * SKn;
  float mx = -INFINITY, sm = 0.f;
  for (int j = 0; j < SKn; ++j) {
    int is = irow[j];
    float p = qd * k[((size_t)((bh << 12) | is)) * 64 + lane];
#pragma unroll
    for (int m2 = 1; m2 < 64; m2 <<= 1) p += __shfl_xor(p, m2, 64);
    mx = fmaxf(mx, p);
    sm += p;
  }
  if (lane == 0) Mout[g] = mx - sm * (1.0f / 4096.0f);
}

// ------------- top-36 per (b,h): repeated block argmax ----------------------
__global__ __launch_bounds__(256) void topk_kernel(
    const float* __restrict__ M, int* __restrict__ topidx) {
  __shared__ float sv[4096];
  __shared__ float rv[256];
  __shared__ int ri[256];
  int bh = blockIdx.x;
  int t = threadIdx.x;
  for (int i = t; i < 4096; i += 256) sv[i] = M[(size_t)bh * 4096 + i];
  __syncthreads();
  for (int u = 0; u < NTOP; ++u) {
    float best = -INFINITY; int bi = 0x7fffffff;
    for (int i = t; i < 4096; i += 256) {
      float v = sv[i];
      if (v > best || (v == best && i < bi)) { best = v; bi = i; }
    }
    rv[t] = best; ri[t] = bi;
    __syncthreads();
    for (int s2 = 128; s2 > 0; s2 >>= 1) {
      if (t < s2) {
        if (rv[t + s2] > rv[t] || (rv[t + s2] == rv[t] && ri[t + s2] < ri[t])) {
          rv[t] = rv[t + s2]; ri[t] = ri[t + s2];
        }
      }
      __syncthreads();
    }
    if (t == 0) { topidx[bh * NTOP + u] = ri[0]; sv[ri[0]] = -INFINITY; }
    __syncthreads();
  }
}

// ------------- v row-sum per (b,h) ------------------------------------------
__global__ __launch_bounds__(64) void vsum_partial(
    const float* __restrict__ v, float* __restrict__ part) {
  int bh = blockIdx.x, ch = blockIdx.y;
  int lane = threadIdx.x;
  float acc = 0.f;
  for (int l = ch * 256; l < ch * 256 + 256; ++l)
    acc += v[((size_t)bh * 4096 + l) * 64 + lane];
  part[((size_t)bh * 16 + ch) * 64 + lane] = acc;
}

__global__ __launch_bounds__(64) void vsum_final(
    const float* __restrict__ part, float* __restrict__ vsum) {
  int bh = blockIdx.x, lane = threadIdx.x;
  float acc = 0.f;
  for (int ch = 0; ch < 16; ++ch) acc += part[((size_t)bh * 16 + ch) * 64 + lane];
  vsum[bh * 64 + lane] = acc;
}

// ------------- attention partials: block per (bh, 64-key chunk) -------------
__global__ __launch_bounds__(256) void attn_partial(
    const float* __restrict__ q, const float* __restrict__ k,
    const float* __restrict__ v, const int* __restrict__ topidx,
    float* __restrict__ part_m, float* __restrict__ part_s,
    float* __restrict__ part_o) {
  __shared__ float4 Ks4[64][17];   // K chunk, stride 17 f4 (odd) -> no b128 conflict
  __shared__ float4 qs4[36][17];   // gathered Q rows
  __shared__ float S[36][68];      // scores -> exp values
  int bh = blockIdx.y;
  int c = blockIdx.x;
  int l0 = c * 64;
  int t = threadIdx.x;
  size_t base = (size_t)bh * 4096;

  const float4* kg = (const float4*)(k + (base + l0) * 64);
  for (int i = t; i < 64 * 16; i += 256) {
    int row = i >> 4, d4 = i & 15;
    Ks4[row][d4] = kg[row * 16 + d4];
  }
  for (int i = t; i < 36 * 16; i += 256) {
    int u = i >> 4, d4 = i & 15;
    int m = topidx[bh * NTOP + u];
    qs4[u][d4] = ((const float4*)(q + (base + m) * 64))[d4];
  }
  __syncthreads();

  // scores: thread (l = t&63, ug = t>>6) computes 9 rows
  {
    int l = t & 63, ug = t >> 6;
    float acc[9] = {};
#pragma unroll
    for (int d4 = 0; d4 < 16; ++d4) {
      float4 kv = Ks4[l][d4];
#pragma unroll
      for (int j = 0; j < 9; ++j) {
        float4 qv = qs4[ug * 9 + j][d4];
        acc[j] += kv.x * qv.x + kv.y * qv.y + kv.z * qv.z + kv.w * qv.w;
      }
    }
#pragma unroll
    for (int j = 0; j < 9; ++j) S[ug * 9 + j][l] = acc[j] * 0.125f;
  }
  __syncthreads();

  // per-row partial softmax (raw max + expsum), threads 0..35
  if (t < NTOP) {
    float mx = -INFINITY;
    for (int l = 0; l < 64; ++l) mx = fmaxf(mx, S[t][l]);
    float sm = 0.f;
    for (int l = 0; l < 64; ++l) { float e = expf(S[t][l] - mx); S[t][l] = e; sm += e; }
    part_m[((size_t)bh * NCHUNK + c) * NTOP + t] = mx;
    part_s[((size_t)bh * NCHUNK + c) * NTOP + t] = sm;
  }
  __syncthreads();

  // partial PV: thread (d = t&63, ug = t>>6) accumulates 9 rows
  {
    int d = t & 63, ug = t >> 6;
    float pacc[9] = {};
    const float* vg = v + (base + l0) * 64;
    for (int l = 0; l < 64; ++l) {
      float vv = vg[l * 64 + d];
#pragma unroll
      for (int j = 0; j < 9; ++j) pacc[j] += S[ug * 9 + j][l] * vv;
    }
#pragma unroll
    for (int j = 0; j < 9; ++j)
      part_o[(((size_t)bh * NCHUNK + c) * NTOP + ug * 9 + j) * 64 + d] = pacc[j];
  }
}

// ------------- combine partials, write straight into ctx --------------------
__global__ __launch_bounds__(256) void attn_combine(
    const float* __restrict__ part_m, const float* __restrict__ part_s,
    const float* __restrict__ part_o, const int* __restrict__ topidx,
    float* __restrict__ ctx) {
  __shared__ float wl[4][64];
  int wave = threadIdx.x >> 6;
  int lane = threadIdx.x & 63;   // lane == chunk index for phase 1, == d for phase 2
  int widx = blockIdx.x * 4 + wave;  // 0..575 = bh*36 + u
  int bh = widx / NTOP;
  int u = widx % NTOP;
  float m_c = part_m[((size_t)bh * NCHUNK + lane) * NTOP + u];
  float M = m_c;
#pragma unroll
  for (int off = 32; off > 0; off >>= 1) M = fmaxf(M, __shfl_xor(M, off, 64));
  float w = expf(m_c - M);
  float ds = part_s[((size_t)bh * NCHUNK + lane) * NTOP + u] * w;
#pragma unroll
  for (int off = 32; off > 0; off >>= 1) ds += __shfl_xor(ds, off, 64);
  wl[wave][lane] = w;
  __syncthreads();
  float acc = 0.f;
  for (int c2 = 0; c2 < NCHUNK; ++c2)
    acc += part_o[(((size_t)bh * NCHUNK + c2) * NTOP + u) * 64 + lane] * wl[wave][c2];
  int m = topidx[bh * NTOP + u];
  ctx[((size_t)bh * 4096 + m) * 64 + lane] = acc / ds;
}

// ------------- ctx = broadcast(vsum) ----------------------------------------
__global__ __launch_bounds__(256) void ctx_fill(
    const float* __restrict__ vsum, float4* __restrict__ ctx4) {
  int i = blockIdx.x * 256 + threadIdx.x;  // over 1,048,576 float4s
  int d4 = i & 15;
  int bh = i >> 16;
  ctx4[i] = ((const float4*)vsum)[bh * 16 + d4];
}

extern "C" void kernel_launch(void* const* d_in, const int* in_sizes, int n_in,
                              void* d_out, int out_size, void* d_ws, size_t ws_size,
                              hipStream_t stream) {
  const float* et  = (const float*)d_in[0];
  const float* mp  = (const float*)d_in[1];
  const float* co  = (const float*)d_in[2];
  const float* vol = (const float*)d_in[3];
  const float* Wq = (const float*)d_in[4];
  const float* bq = (const float*)d_in[5];
  const float* Wk = (const float*)d_in[6];
  const float* bk = (const float*)d_in[7];
  const float* Wv = (const float*)d_in[8];
  const float* bv = (const float*)d_in[9];
  const float* Wo = (const float*)d_in[10];
  const float* bo = (const float*)d_in[11];
  const int* idxs = (const int*)d_in[12];
  float* out = (float*)d_out;

  char* ws = (char*)d_ws;
  const size_t BIG = 16u * 1024u * 1024u;
  float* qb = (float*)(ws);            // Q, later reused as ctx
  float* kb = (float*)(ws + BIG);
  float* vb = (float*)(ws + 2 * BIG);
  char* sm = ws + 3 * BIG;
  float* Mbuf   = (float*)(sm);                                  // 256 KB
  int*   topidx = (int*)(sm + 262144);                           // ~2.3 KB (pad 4K)
  float* vpart  = (float*)(sm + 262144 + 4096);                  // 64 KB
  float* vsum   = (float*)(sm + 262144 + 4096 + 65536);          // 4 KB
  char* pm = sm + 262144 + 4096 + 65536 + 4096;
  float* part_m = (float*)(pm);                                  // 16*64*36*4 = 144 KB
  float* part_s = (float*)(pm + 147456);                         // 144 KB
  float* part_o = (float*)(pm + 2 * 147456);                     // 16*64*36*64*4 = 9.4 MB

  // fused QKV projection (gathered A), 128x128 tiles
  gemm128<<<dim3(6, 128), 256, 0, stream>>>(
      nullptr, Wq, Wk, Wv, bq, bk, bv, qb, kb, vb, et, co, mp, vol, 1);

  // sampled scores -> sparsity measure M (exact f32 — selection-critical)
  qks_m<<<16384, 256, 0, stream>>>(qb, kb, idxs, Mbuf);

  // top-36 per (b,h)
  topk_kernel<<<BHn, 256, 0, stream>>>(Mbuf, topidx);

  // v column sums
  vsum_partial<<<dim3(BHn, 16), 64, 0, stream>>>(vb, vpart);
  vsum_final<<<BHn, 64, 0, stream>>>(vpart, vsum);

  // flash-style attention over selected rows
  attn_partial<<<dim3(NCHUNK, BHn), 256, 0, stream>>>(
      qb, kb, vb, topidx, part_m, part_s, part_o);

  // ctx = broadcast(vsum) into qb's buffer (Q dead after attn_partial)
  ctx_fill<<<4096, 256, 0, stream>>>(vsum, (float4*)qb);

  // merge partials, scatter results into ctx
  attn_combine<<<144, 256, 0, stream>>>(part_m, part_s, part_o, topidx, qb);

  // output projection
  gemm128<<<dim3(2, 128), 256, 0, stream>>>(
      qb, Wo, Wo, Wo, bo, bo, bo, out, out, out, nullptr, nullptr, nullptr, nullptr, 0);
}

// Round 4
// 237.171 us; speedup vs baseline: 4.3420x; 1.8076x over previous
//
#include <hip/hip_runtime.h>
#include <hip/hip_bf16.h>

// Shapes (fixed): B=4, SEQ=1024, C=256, H=4, Dk=64, L=4096, N_TOP=SAMPLE_K=36
#define BHn 16
#define Ln 4096
#define NTOP 36
#define SKn 36
#define NCHUNK 64   // l-chunks of 64 for attn partials

// ---------------- GEMM: O = A(16384x256) @ W(256x256) + bias ----------------
// 128x128 tile, 256 threads, 8x8 micro-tile. Fused QKV via blockIdx.x>>1.
__global__ __launch_bounds__(256) void gemm128(
    const float* __restrict__ A,
    const float* __restrict__ W0, const float* __restrict__ W1, const float* __restrict__ W2,
    const float* __restrict__ b0, const float* __restrict__ b1, const float* __restrict__ b2,
    float* __restrict__ o0, float* __restrict__ o1, float* __restrict__ o2,
    const float* __restrict__ s0, const float* __restrict__ s1,
    const float* __restrict__ s2, const float* __restrict__ s3,
    int gather) {
  __shared__ float As[16][136];
  __shared__ float Bs[16][132];
  int t = threadIdx.x;
  int w = blockIdx.x >> 1;
  int col0 = (blockIdx.x & 1) * 128;
  int row0 = blockIdx.y * 128;
  const float* W = (w == 0) ? W0 : (w == 1) ? W1 : W2;
  const float* bias = (w == 0) ? b0 : (w == 1) ? b1 : b2;
  float* O = (w == 0) ? o0 : (w == 1) ? o1 : o2;
  int tx = t & 15, ty = t >> 4;

  int arow = row0 + (t >> 1);
  int kh = (t & 1) * 8;
  const float* abase;
  if (gather) {
    int l = arow & 4095, b = arow >> 12;
    int part = (l >> 2) & 3;
    int seq = ((l >> 4) << 2) | (l & 3);
    const float* sp = (part == 0) ? s0 : (part == 1) ? s1 : (part == 2) ? s2 : s3;
    abase = sp + (size_t)((b << 10) + seq) * 256;
  } else {
    abase = A + (size_t)arow * 256;
  }
  int kk = t >> 4;

  float acc[8][8] = {};
  for (int k0 = 0; k0 < 256; k0 += 16) {
    float4 a0 = ((const float4*)(abase + k0 + kh))[0];
    float4 a1 = ((const float4*)(abase + k0 + kh))[1];
    int r = t >> 1;
    As[kh + 0][r] = a0.x; As[kh + 1][r] = a0.y; As[kh + 2][r] = a0.z; As[kh + 3][r] = a0.w;
    As[kh + 4][r] = a1.x; As[kh + 5][r] = a1.y; As[kh + 6][r] = a1.z; As[kh + 7][r] = a1.w;
    const float* wrow = W + (size_t)(k0 + kk) * 256 + col0 + tx * 8;
    float4 bb0 = ((const float4*)wrow)[0];
    float4 bb1 = ((const float4*)wrow)[1];
    *((float4*)&Bs[kk][tx * 8]) = bb0;
    *((float4*)&Bs[kk][tx * 8 + 4]) = bb1;
    __syncthreads();
#pragma unroll
    for (int k2 = 0; k2 < 16; ++k2) {
      float av[8], bv[8];
      *(float4*)&av[0] = *(const float4*)&As[k2][ty * 8];
      *(float4*)&av[4] = *(const float4*)&As[k2][ty * 8 + 4];
      *(float4*)&bv[0] = *(const float4*)&Bs[k2][tx * 8];
      *(float4*)&bv[4] = *(const float4*)&Bs[k2][tx * 8 + 4];
#pragma unroll
      for (int i = 0; i < 8; ++i)
#pragma unroll
        for (int j = 0; j < 8; ++j) acc[i][j] += av[i] * bv[j];
    }
    __syncthreads();
  }
#pragma unroll
  for (int i = 0; i < 8; ++i) {
    int row = row0 + ty * 8 + i;
    float* orow = O + (size_t)row * 256 + col0 + tx * 8;
#pragma unroll
    for (int j = 0; j < 8; ++j) acc[i][j] += bias[col0 + tx * 8 + j];
    ((float4*)orow)[0] = *(float4*)&acc[i][0];
    ((float4*)orow)[1] = *(float4*)&acc[i][4];
  }
}

// ------------- sampled QK^T and M: block per (bh, 64-s chunk) ---------------
__global__ __launch_bounds__(256) void qks_m2(
    const float* __restrict__ q, const float* __restrict__ k,
    const int* __restrict__ idxs, float* __restrict__ Mout) {
  __shared__ float qs[64][68];
  __shared__ int il[64 * SKn];
  int bh = blockIdx.y;
  int s0 = blockIdx.x * 64;
  int t = threadIdx.x;
  size_t base = (size_t)bh << 12;
  for (int i = t; i < 1024; i += 256) {
    int row = i >> 4, d4 = i & 15;
    *(float4*)&qs[row][d4 * 4] = ((const float4*)(q + (base + s0 + row) * 64))[d4];
  }
  for (int i = t; i < 64 * SKn; i += 256) il[i] = idxs[s0 * SKn + i];
  __syncthreads();
  int sl = t >> 2;
  int dq = t & 3;
  float qr[16];
#pragma unroll
  for (int i = 0; i < 4; ++i)
    *(float4*)&qr[i * 4] = *(const float4*)&qs[sl][i * 16 + dq * 4];
  float mx = -INFINITY, sm = 0.f;
  const float4* kb4 = (const float4*)(k + base * 64);
#pragma unroll 4
  for (int j = 0; j < SKn; ++j) {
    int l = il[sl * SKn + j];
    const float4* kr = kb4 + (size_t)l * 16;
    float acc = 0.f;
#pragma unroll
    for (int i = 0; i < 4; ++i) {
      float4 kv = kr[i * 4 + dq];
      acc += kv.x * qr[i * 4] + kv.y * qr[i * 4 + 1] + kv.z * qr[i * 4 + 2] + kv.w * qr[i * 4 + 3];
    }
    acc += __shfl_xor(acc, 1, 64);
    acc += __shfl_xor(acc, 2, 64);
    mx = fmaxf(mx, acc);
    sm += acc;
  }
  if (dq == 0) Mout[base + s0 + sl] = mx - sm * (1.0f / 4096.0f);
}

// ------------- top-36 per (b,h): two-phase radix select ---------------------
__global__ __launch_bounds__(256) void topk_radix(
    const float* __restrict__ M, int* __restrict__ topidx) {
  __shared__ unsigned hist[4096];
  __shared__ unsigned sup[256];
  __shared__ unsigned cand_u[256];
  __shared__ int cand_i[256];
  __shared__ int s_bin1, s_bin2, s_above, s_ocnt, s_ccnt;
  int bh = blockIdx.x;
  int t = threadIdx.x;
  int mbase = bh * 4096;
  unsigned uv[16];
  for (int i = t; i < 4096; i += 256) hist[i] = 0;
  __syncthreads();
#pragma unroll
  for (int r = 0; r < 16; ++r) {
    unsigned b = __float_as_uint(M[mbase + t + 256 * r]);
    unsigned u = b ^ ((unsigned)((int)b >> 31) | 0x80000000u);
    uv[r] = u;
    atomicAdd(&hist[u >> 20], 1u);
  }
  __syncthreads();
  {
    unsigned ssum = 0;
    for (int i = 0; i < 16; ++i) ssum += hist[t * 16 + i];
    sup[t] = ssum;
  }
  __syncthreads();
  if (t == 0) {
    unsigned cum = 0; int sb = 255;
    for (; sb > 0; --sb) { if (cum + sup[sb] >= NTOP) break; cum += sup[sb]; }
    int b = sb * 16 + 15;
    for (; b > sb * 16; --b) { if (cum + hist[b] >= NTOP) break; cum += hist[b]; }
    s_bin1 = b; s_above = (int)cum;
  }
  __syncthreads();
  int bin1 = s_bin1;
  int need1 = NTOP - s_above;
  __syncthreads();
  for (int i = t; i < 4096; i += 256) hist[i] = 0;
  __syncthreads();
#pragma unroll
  for (int r = 0; r < 16; ++r)
    if ((int)(uv[r] >> 20) == bin1) atomicAdd(&hist[(uv[r] >> 8) & 0xFFF], 1u);
  __syncthreads();
  {
    unsigned ssum = 0;
    for (int i = 0; i < 16; ++i) ssum += hist[t * 16 + i];
    sup[t] = ssum;
  }
  __syncthreads();
  if (t == 0) {
    unsigned cum = 0; int sb = 255;
    for (; sb > 0; --sb) { if (cum + sup[sb] >= (unsigned)need1) break; cum += sup[sb]; }
    int b = sb * 16 + 15;
    for (; b > sb * 16; --b) { if (cum + hist[b] >= (unsigned)need1) break; cum += hist[b]; }
    s_bin2 = b; s_above += (int)cum;
    s_ocnt = 0; s_ccnt = 0;
  }
  __syncthreads();
  int bin2 = s_bin2;
  int need = NTOP - s_above;
  int* outp = topidx + bh * NTOP;
#pragma unroll
  for (int r = 0; r < 16; ++r) {
    unsigned u = uv[r];
    int b1 = u >> 20, b2 = (u >> 8) & 0xFFF;
    if (b1 > bin1 || (b1 == bin1 && b2 > bin2)) {
      int p = atomicAdd(&s_ocnt, 1);
      outp[p] = t + 256 * r;
    } else if (b1 == bin1 && b2 == bin2) {
      int p = atomicAdd(&s_ccnt, 1);
      if (p < 256) { cand_u[p] = u; cand_i[p] = t + 256 * r; }
    }
  }
  __syncthreads();
  if (t == 0) {
    int cc = s_ccnt < 256 ? s_ccnt : 256;
    int slot = s_ocnt;
    for (int n = 0; n < need; ++n) {
      unsigned bu = 0; int bi = 0x7fffffff, bp = -1;
      for (int c = 0; c < cc; ++c) {
        if (cand_i[c] < 0) continue;
        if (cand_u[c] > bu || (cand_u[c] == bu && cand_i[c] < bi)) {
          bu = cand_u[c]; bi = cand_i[c]; bp = c;
        }
      }
      outp[slot++] = bi;
      cand_i[bp] = -1;
    }
  }
}

// ------------- v row-sum per (b,h) ------------------------------------------
__global__ __launch_bounds__(256) void vsum_partial(
    const float* __restrict__ v, float* __restrict__ part) {
  __shared__ float4 red[256];
  int bh = blockIdx.x, ch = blockIdx.y;
  int t = threadIdx.x;
  int rg = t >> 4, d4 = t & 15;
  const float4* v4 = (const float4*)(v + ((size_t)bh * 4096 + ch * 256) * 64);
  float4 acc = {0.f, 0.f, 0.f, 0.f};
  for (int r = rg; r < 256; r += 16) {
    float4 x = v4[r * 16 + d4];
    acc.x += x.x; acc.y += x.y; acc.z += x.z; acc.w += x.w;
  }
  red[t] = acc;
  __syncthreads();
  for (int s2 = 8; s2 > 0; s2 >>= 1) {
    if (rg < s2) {
      float4 o = red[(rg + s2) * 16 + d4];
      red[t].x += o.x; red[t].y += o.y; red[t].z += o.z; red[t].w += o.w;
    }
    __syncthreads();
  }
  if (rg == 0) ((float4*)part)[((size_t)bh * 16 + ch) * 16 + d4] = red[d4];
}

__global__ __launch_bounds__(64) void vsum_final(
    const float* __restrict__ part, float* __restrict__ vsum) {
  int bh = blockIdx.x, lane = threadIdx.x;
  float acc = 0.f;
  for (int ch = 0; ch < 16; ++ch) acc += part[((size_t)bh * 16 + ch) * 64 + lane];
  vsum[bh * 64 + lane] = acc;
}

// ------------- attention partials: block per (bh, 64-key chunk) -------------
__global__ __launch_bounds__(256) void attn_partial(
    const float* __restrict__ q, const float* __restrict__ k,
    const float* __restrict__ v, const int* __restrict__ topidx,
    float* __restrict__ part_m, float* __restrict__ part_s,
    float* __restrict__ part_o) {
  __shared__ float4 Ks4[64][17];
  __shared__ float4 qs4[36][17];
  __shared__ float S[36][68];
  int bh = blockIdx.y;
  int c = blockIdx.x;
  int l0 = c * 64;
  int t = threadIdx.x;
  size_t base = (size_t)bh * 4096;

  const float4* kg = (const float4*)(k + (base + l0) * 64);
  for (int i = t; i < 64 * 16; i += 256) {
    int row = i >> 4, d4 = i & 15;
    Ks4[row][d4] = kg[row * 16 + d4];
  }
  for (int i = t; i < 36 * 16; i += 256) {
    int u = i >> 4, d4 = i & 15;
    int m = topidx[bh * NTOP + u];
    qs4[u][d4] = ((const float4*)(q + (base + m) * 64))[d4];
  }
  __syncthreads();

  {
    int l = t & 63, ug = t >> 6;
    float acc[9] = {};
#pragma unroll
    for (int d4 = 0; d4 < 16; ++d4) {
      float4 kv = Ks4[l][d4];
#pragma unroll
      for (int j = 0; j < 9; ++j) {
        float4 qv = qs4[ug * 9 + j][d4];
        acc[j] += kv.x * qv.x + kv.y * qv.y + kv.z * qv.z + kv.w * qv.w;
      }
    }
#pragma unroll
    for (int j = 0; j < 9; ++j) S[ug * 9 + j][l] = acc[j] * 0.125f;
  }
  __syncthreads();

  if (t < NTOP) {
    float mx = -INFINITY;
    for (int l = 0; l < 64; ++l) mx = fmaxf(mx, S[t][l]);
    float sm = 0.f;
    for (int l = 0; l < 64; ++l) { float e = expf(S[t][l] - mx); S[t][l] = e; sm += e; }
    part_m[((size_t)bh * NCHUNK + c) * NTOP + t] = mx;
    part_s[((size_t)bh * NCHUNK + c) * NTOP + t] = sm;
  }
  __syncthreads();

  {
    int d = t & 63, ug = t >> 6;
    float pacc[9] = {};
    const float* vg = v + (base + l0) * 64;
    for (int l = 0; l < 64; ++l) {
      float vv = vg[l * 64 + d];
#pragma unroll
      for (int j = 0; j < 9; ++j) pacc[j] += S[ug * 9 + j][l] * vv;
    }
#pragma unroll
    for (int j = 0; j < 9; ++j)
      part_o[(((size_t)bh * NCHUNK + c) * NTOP + ug * 9 + j) * 64 + d] = pacc[j];
  }
}

// ------------- combine partials -> upd --------------------------------------
__global__ __launch_bounds__(256) void attn_combine(
    const float* __restrict__ part_m, const float* __restrict__ part_s,
    const float* __restrict__ part_o, float* __restrict__ upd) {
  __shared__ float wl[4][64];
  int wave = threadIdx.x >> 6;
  int lane = threadIdx.x & 63;
  int widx = blockIdx.x * 4 + wave;  // bh*36 + u
  int bh = widx / NTOP;
  int u = widx % NTOP;
  float m_c = part_m[((size_t)bh * NCHUNK + lane) * NTOP + u];
  float M = m_c;
#pragma unroll
  for (int off = 32; off > 0; off >>= 1) M = fmaxf(M, __shfl_xor(M, off, 64));
  float w = expf(m_c - M);
  float ds = part_s[((size_t)bh * NCHUNK + lane) * NTOP + u] * w;
#pragma unroll
  for (int off = 32; off > 0; off >>= 1) ds += __shfl_xor(ds, off, 64);
  wl[wave][lane] = w;
  __syncthreads();
  float acc = 0.f;
  for (int c2 = 0; c2 < NCHUNK; ++c2)
    acc += part_o[(((size_t)bh * NCHUNK + c2) * NTOP + u) * 64 + lane] * wl[wave][c2];
  upd[(size_t)widx * 64 + lane] = acc / ds;
}

// ------------- output path --------------------------------------------------
// ctx.reshape(sz, L, H*Dk): reshaped row l' = h*1024 + l/4 holds head h's ctx
// rows 4*(l'%1024)+j (j=0..3) in column blocks j*64..j*64+63.
// Non-selected rows: all four blocks = vsum[b,h] ->
//   base[bh] = bo + vsum[bh] @ (Wo[0:64] + Wo[64:128] + Wo[128:192] + Wo[192:256])
__global__ __launch_bounds__(256) void out_base(
    const float* __restrict__ vsum, const float* __restrict__ Wo,
    const float* __restrict__ bo, float* __restrict__ outbase) {
  __shared__ float xb[64];
  int bh = blockIdx.x, c = threadIdx.x;
  if (c < 64) xb[c] = vsum[bh * 64 + c];
  __syncthreads();
  float acc = bo[c];
#pragma unroll 8
  for (int d = 0; d < 64; ++d) {
    float w4 = Wo[d * 256 + c] + Wo[(64 + d) * 256 + c] +
               Wo[(128 + d) * 256 + c] + Wo[(192 + d) * 256 + c];
    acc += xb[d] * w4;
  }
  outbase[bh * 256 + c] = acc;
}

__global__ __launch_bounds__(256) void out_fill(
    const float* __restrict__ outbase, float4* __restrict__ out4) {
  int g = blockIdx.x * 256 + threadIdx.x;   // over 1,048,576 float4
  int c4 = g & 63;
  int bh = g >> 16;                          // row = g>>6; bh = row>>10
  out4[g] = ((const float4*)outbase)[bh * 64 + c4];
}

// Selected l=m (head h, batch b): reshaped row l' = h*1024 + m/4, block j = m%4:
//   out[b, l'] += (upd - vsum[bh]) @ Wo[j*64 : (j+1)*64]
__global__ __launch_bounds__(256) void out_patch(
    const float* __restrict__ upd, const float* __restrict__ vsum,
    const int* __restrict__ topidx, const float* __restrict__ Wo,
    float* __restrict__ out) {
  __shared__ float dv[64];
  int bhu = blockIdx.x;
  int bh = bhu / NTOP;
  int h = bh & 3, b = bh >> 2;
  int t = threadIdx.x;
  if (t < 64) dv[t] = upd[(size_t)bhu * 64 + t] - vsum[bh * 64 + t];
  __syncthreads();
  int m = topidx[bhu];
  int j = m & 3;
  int lp = h * 1024 + (m >> 2);
  float acc = 0.f;
#pragma unroll 8
  for (int d = 0; d < 64; ++d) acc += dv[d] * Wo[(j * 64 + d) * 256 + t];
  atomicAdd(&out[((size_t)(b * 4096 + lp)) * 256 + t], acc);
}

extern "C" void kernel_launch(void* const* d_in, const int* in_sizes, int n_in,
                              void* d_out, int out_size, void* d_ws, size_t ws_size,
                              hipStream_t stream) {
  const float* et  = (const float*)d_in[0];
  const float* mp  = (const float*)d_in[1];
  const float* co  = (const float*)d_in[2];
  const float* vol = (const float*)d_in[3];
  const float* Wq = (const float*)d_in[4];
  const float* bq = (const float*)d_in[5];
  const float* Wk = (const float*)d_in[6];
  const float* bk = (const float*)d_in[7];
  const float* Wv = (const float*)d_in[8];
  const float* bv = (const float*)d_in[9];
  const float* Wo = (const float*)d_in[10];
  const float* bo = (const float*)d_in[11];
  const int* idxs = (const int*)d_in[12];
  float* out = (float*)d_out;

  char* ws = (char*)d_ws;
  const size_t BIG = 16u * 1024u * 1024u;
  float* qb = (float*)(ws);
  float* kb = (float*)(ws + BIG);
  float* vb = (float*)(ws + 2 * BIG);
  char* sm = ws + 3 * BIG;
  float* Mbuf   = (float*)(sm);                                  // 256 KB
  int*   topidx = (int*)(sm + 262144);                           // pad 4 KB
  float* vpart  = (float*)(sm + 262144 + 4096);                  // 64 KB
  float* vsum   = (float*)(sm + 262144 + 4096 + 65536);          // 4 KB
  char* pm = sm + 262144 + 4096 + 65536 + 4096;
  float* part_m = (float*)(pm);                                  // 144 KB
  float* part_s = (float*)(pm + 147456);                         // 144 KB
  float* part_o = (float*)(pm + 2 * 147456);                     // 9.4 MB
  float* updb   = (float*)(pm + 2 * 147456 + 9437184);           // 144 KB
  float* outbase = (float*)(pm + 2 * 147456 + 9437184 + 147456); // 16 KB

  // fused QKV projection (gathered A), 128x128 tiles
  gemm128<<<dim3(6, 128), 256, 0, stream>>>(
      nullptr, Wq, Wk, Wv, bq, bk, bv, qb, kb, vb, et, co, mp, vol, 1);

  // sampled scores -> sparsity measure M (exact f32 — selection-critical)
  qks_m2<<<dim3(64, BHn), 256, 0, stream>>>(qb, kb, idxs, Mbuf);

  // top-36 per (b,h), radix select
  topk_radix<<<BHn, 256, 0, stream>>>(Mbuf, topidx);

  // v column sums
  vsum_partial<<<dim3(BHn, 16), 256, 0, stream>>>(vb, vpart);
  vsum_final<<<BHn, 64, 0, stream>>>(vpart, vsum);

  // flash-style attention over selected rows
  attn_partial<<<dim3(NCHUNK, BHn), 256, 0, stream>>>(
      qb, kb, vb, topidx, part_m, part_s, part_o);
  attn_combine<<<144, 256, 0, stream>>>(part_m, part_s, part_o, updb);

  // output: per-(b,h) base rows, broadcast fill, sparse rank-update patches
  out_base<<<BHn, 256, 0, stream>>>(vsum, Wo, bo, outbase);
  out_fill<<<4096, 256, 0, stream>>>(outbase, (float4*)out);
  out_patch<<<BHn * NTOP, 256, 0, stream>>>(updb, vsum, topidx, Wo, out);
}

// Round 5
// 189.229 us; speedup vs baseline: 5.4421x; 1.2534x over previous
//
#include <hip/hip_runtime.h>
#include <hip/hip_bf16.h>

// Shapes (fixed): B=4, SEQ=1024, C=256, H=4, Dk=64, L=4096, N_TOP=SAMPLE_K=36
#define BHn 16
#define Ln 4096
#define NTOP 36
#define SKn 36
#define NCHUNK 64   // l-chunks of 64 for attn partials

using s16x8 = __attribute__((ext_vector_type(8))) short;
using u16x8 = __attribute__((ext_vector_type(8))) unsigned short;
using f32x4 = __attribute__((ext_vector_type(4))) float;

__device__ __forceinline__ unsigned short bf_hi(float f) {
  unsigned u = __float_as_uint(f);
  return (unsigned short)((u + 0x7fffu + ((u >> 16) & 1u)) >> 16);
}

// ---------- W[k][n] f32 -> Wt_hi[n][k], Wt_lo[n][k] bf16 (transposed) -------
__global__ __launch_bounds__(256) void wconv(
    const float* __restrict__ W0, const float* __restrict__ W1, const float* __restrict__ W2,
    unsigned short* __restrict__ th0, unsigned short* __restrict__ tl0,
    unsigned short* __restrict__ th1, unsigned short* __restrict__ tl1,
    unsigned short* __restrict__ th2, unsigned short* __restrict__ tl2) {
  int wsel = blockIdx.y;
  const float* W = (wsel == 0) ? W0 : (wsel == 1) ? W1 : W2;
  unsigned short* TH = (wsel == 0) ? th0 : (wsel == 1) ? th1 : th2;
  unsigned short* TL = (wsel == 0) ? tl0 : (wsel == 1) ? tl1 : tl2;
  int kr = blockIdx.x * 16;
  int n = threadIdx.x;
  u16x8 hv[2], lv[2];
#pragma unroll
  for (int j = 0; j < 16; ++j) {
    float f = W[(size_t)(kr + j) * 256 + n];
    unsigned short h = bf_hi(f);
    float lof = f - __uint_as_float(((unsigned)h) << 16);
    hv[j >> 3][j & 7] = h;
    lv[j >> 3][j & 7] = bf_hi(lof);
  }
  *(u16x8*)&TH[(size_t)n * 256 + kr] = hv[0];
  *(u16x8*)&TH[(size_t)n * 256 + kr + 8] = hv[1];
  *(u16x8*)&TL[(size_t)n * 256 + kr] = lv[0];
  *(u16x8*)&TL[(size_t)n * 256 + kr + 8] = lv[1];
}

// ---------- QKV projection: split-bf16 MFMA, 128x128 tile, BK=32 ------------
// O = gather(x) @ W + b ~= Ah*Bh + Ah*Bl + Al*Bh  (f32 accumulate)
#define LDW 40   // bf16 elems per LDS row (32 used + 8 pad) -> 80B stride
__global__ __launch_bounds__(256, 2) void qkv_mfma(
    const unsigned short* __restrict__ th0, const unsigned short* __restrict__ tl0,
    const unsigned short* __restrict__ th1, const unsigned short* __restrict__ tl1,
    const unsigned short* __restrict__ th2, const unsigned short* __restrict__ tl2,
    const float* __restrict__ b0, const float* __restrict__ b1, const float* __restrict__ b2,
    float* __restrict__ o0, float* __restrict__ o1, float* __restrict__ o2,
    const float* __restrict__ s0, const float* __restrict__ s1,
    const float* __restrict__ s2, const float* __restrict__ s3) {
  __shared__ __align__(16) unsigned short Ah[128 * LDW];
  __shared__ __align__(16) unsigned short Al[128 * LDW];
  __shared__ __align__(16) unsigned short Bh[128 * LDW];
  __shared__ __align__(16) unsigned short Bl[128 * LDW];
  int t = threadIdx.x;
  int wsel = blockIdx.x >> 1;
  int col0 = (blockIdx.x & 1) * 128;
  int row0 = blockIdx.y * 128;
  const unsigned short* TH = (wsel == 0) ? th0 : (wsel == 1) ? th1 : th2;
  const unsigned short* TL = (wsel == 0) ? tl0 : (wsel == 1) ? tl1 : tl2;
  const float* bias = (wsel == 0) ? b0 : (wsel == 1) ? b1 : b2;
  float* O = (wsel == 0) ? o0 : (wsel == 1) ? o1 : o2;

  // staging assignment: row = t>>1 (0..127), half = t&1 (16 k-elems)
  int srow = t >> 1, half = t & 1;
  int arow = row0 + srow;
  const float* abase;
  {
    int l = arow & 4095, b = arow >> 12;
    int part = (l >> 2) & 3;
    int seq = ((l >> 4) << 2) | (l & 3);
    const float* sp = (part == 0) ? s0 : (part == 1) ? s1 : (part == 2) ? s2 : s3;
    abase = sp + (size_t)((b << 10) + seq) * 256;
  }
  const unsigned short* bh_g = TH + (size_t)(col0 + srow) * 256 + half * 16;
  const unsigned short* bl_g = TL + (size_t)(col0 + srow) * 256 + half * 16;

  int lane = t & 63;
  int wv = t >> 6;
  int wr = wv >> 1, wc = wv & 1;
  int fr = lane & 15, fk = lane >> 4;   // fragment row/col, k-subgroup
  int aoff = (wr * 64 + fr) * LDW + fk * 8;
  int boff = (wc * 64 + fr) * LDW + fk * 8;

  f32x4 acc[4][4] = {};

  for (int k0 = 0; k0 < 256; k0 += 32) {
    // --- stage A (gathered f32 -> hi/lo bf16) ---
    const float* ap = abase + k0 + half * 16;
    float4 f0 = ((const float4*)ap)[0];
    float4 f1 = ((const float4*)ap)[1];
    float4 f2 = ((const float4*)ap)[2];
    float4 f3 = ((const float4*)ap)[3];
    float fv[16];
    *(float4*)&fv[0] = f0; *(float4*)&fv[4] = f1;
    *(float4*)&fv[8] = f2; *(float4*)&fv[12] = f3;
    u16x8 hv[2], lv[2];
#pragma unroll
    for (int j = 0; j < 16; ++j) {
      unsigned short h = bf_hi(fv[j]);
      float lof = fv[j] - __uint_as_float(((unsigned)h) << 16);
      hv[j >> 3][j & 7] = h;
      lv[j >> 3][j & 7] = bf_hi(lof);
    }
    int wa = srow * LDW + half * 16;
    *(u16x8*)&Ah[wa] = hv[0]; *(u16x8*)&Ah[wa + 8] = hv[1];
    *(u16x8*)&Al[wa] = lv[0]; *(u16x8*)&Al[wa + 8] = lv[1];
    // --- stage B (pre-transposed bf16, straight copy) ---
    u16x8 wbh0 = *(const u16x8*)(bh_g + k0);
    u16x8 wbh1 = *(const u16x8*)(bh_g + k0 + 8);
    u16x8 wbl0 = *(const u16x8*)(bl_g + k0);
    u16x8 wbl1 = *(const u16x8*)(bl_g + k0 + 8);
    *(u16x8*)&Bh[wa] = wbh0; *(u16x8*)&Bh[wa + 8] = wbh1;
    *(u16x8*)&Bl[wa] = wbl0; *(u16x8*)&Bl[wa + 8] = wbl1;
    __syncthreads();

    // --- fragments + 48 MFMA ---
    s16x8 fah[4], fal[4], fbh[4], fbl[4];
#pragma unroll
    for (int mi = 0; mi < 4; ++mi) {
      fah[mi] = *(const s16x8*)&Ah[aoff + mi * 16 * LDW];
      fal[mi] = *(const s16x8*)&Al[aoff + mi * 16 * LDW];
    }
#pragma unroll
    for (int ni = 0; ni < 4; ++ni) {
      fbh[ni] = *(const s16x8*)&Bh[boff + ni * 16 * LDW];
      fbl[ni] = *(const s16x8*)&Bl[boff + ni * 16 * LDW];
    }
#pragma unroll
    for (int ni = 0; ni < 4; ++ni) {
#pragma unroll
      for (int mi = 0; mi < 4; ++mi) {
        acc[mi][ni] = __builtin_amdgcn_mfma_f32_16x16x32_bf16(fah[mi], fbh[ni], acc[mi][ni], 0, 0, 0);
        acc[mi][ni] = __builtin_amdgcn_mfma_f32_16x16x32_bf16(fal[mi], fbh[ni], acc[mi][ni], 0, 0, 0);
        acc[mi][ni] = __builtin_amdgcn_mfma_f32_16x16x32_bf16(fah[mi], fbl[ni], acc[mi][ni], 0, 0, 0);
      }
    }
    __syncthreads();
  }

  // epilogue: C/D layout col = lane&15, row = (lane>>4)*4 + reg
#pragma unroll
  for (int ni = 0; ni < 4; ++ni) {
    int n = col0 + wc * 64 + ni * 16 + fr;
    float bv = bias[n];
#pragma unroll
    for (int mi = 0; mi < 4; ++mi) {
      int mb = row0 + wr * 64 + mi * 16 + fk * 4;
#pragma unroll
      for (int r = 0; r < 4; ++r)
        O[(size_t)(mb + r) * 256 + n] = acc[mi][ni][r] + bv;
    }
  }
}

// ------------- sampled QK^T and M: block per (bh, 64-s chunk) ---------------
__global__ __launch_bounds__(256) void qks_m2(
    const float* __restrict__ q, const float* __restrict__ k,
    const int* __restrict__ idxs, float* __restrict__ Mout) {
  __shared__ float qs[64][68];
  __shared__ int il[64 * SKn];
  int bh = blockIdx.y;
  int s0 = blockIdx.x * 64;
  int t = threadIdx.x;
  size_t base = (size_t)bh << 12;
  for (int i = t; i < 1024; i += 256) {
    int row = i >> 4, d4 = i & 15;
    *(float4*)&qs[row][d4 * 4] = ((const float4*)(q + (base + s0 + row) * 64))[d4];
  }
  for (int i = t; i < 64 * SKn; i += 256) il[i] = idxs[s0 * SKn + i];
  __syncthreads();
  int sl = t >> 2;
  int dq = t & 3;
  float qr[16];
#pragma unroll
  for (int i = 0; i < 4; ++i)
    *(float4*)&qr[i * 4] = *(const float4*)&qs[sl][i * 16 + dq * 4];
  float mx = -INFINITY, sm = 0.f;
  const float4* kb4 = (const float4*)(k + base * 64);
#pragma unroll 4
  for (int j = 0; j < SKn; ++j) {
    int l = il[sl * SKn + j];
    const float4* kr = kb4 + (size_t)l * 16;
    float acc = 0.f;
#pragma unroll
    for (int i = 0; i < 4; ++i) {
      float4 kv = kr[i * 4 + dq];
      acc += kv.x * qr[i * 4] + kv.y * qr[i * 4 + 1] + kv.z * qr[i * 4 + 2] + kv.w * qr[i * 4 + 3];
    }
    acc += __shfl_xor(acc, 1, 64);
    acc += __shfl_xor(acc, 2, 64);
    mx = fmaxf(mx, acc);
    sm += acc;
  }
  if (dq == 0) Mout[base + s0 + sl] = mx - sm * (1.0f / 4096.0f);
}

// ------------- top-36 per (b,h): two-phase radix select ---------------------
__global__ __launch_bounds__(256) void topk_radix(
    const float* __restrict__ M, int* __restrict__ topidx) {
  __shared__ unsigned hist[4096];
  __shared__ unsigned sup[256];
  __shared__ unsigned cand_u[256];
  __shared__ int cand_i[256];
  __shared__ int s_bin1, s_bin2, s_above, s_ocnt, s_ccnt;
  int bh = blockIdx.x;
  int t = threadIdx.x;
  int mbase = bh * 4096;
  unsigned uv[16];
  for (int i = t; i < 4096; i += 256) hist[i] = 0;
  __syncthreads();
#pragma unroll
  for (int r = 0; r < 16; ++r) {
    unsigned b = __float_as_uint(M[mbase + t + 256 * r]);
    unsigned u = b ^ ((unsigned)((int)b >> 31) | 0x80000000u);
    uv[r] = u;
    atomicAdd(&hist[u >> 20], 1u);
  }
  __syncthreads();
  {
    unsigned ssum = 0;
    for (int i = 0; i < 16; ++i) ssum += hist[t * 16 + i];
    sup[t] = ssum;
  }
  __syncthreads();
  if (t == 0) {
    unsigned cum = 0; int sb = 255;
    for (; sb > 0; --sb) { if (cum + sup[sb] >= NTOP) break; cum += sup[sb]; }
    int b = sb * 16 + 15;
    for (; b > sb * 16; --b) { if (cum + hist[b] >= NTOP) break; cum += hist[b]; }
    s_bin1 = b; s_above = (int)cum;
  }
  __syncthreads();
  int bin1 = s_bin1;
  int need1 = NTOP - s_above;
  __syncthreads();
  for (int i = t; i < 4096; i += 256) hist[i] = 0;
  __syncthreads();
#pragma unroll
  for (int r = 0; r < 16; ++r)
    if ((int)(uv[r] >> 20) == bin1) atomicAdd(&hist[(uv[r] >> 8) & 0xFFF], 1u);
  __syncthreads();
  {
    unsigned ssum = 0;
    for (int i = 0; i < 16; ++i) ssum += hist[t * 16 + i];
    sup[t] = ssum;
  }
  __syncthreads();
  if (t == 0) {
    unsigned cum = 0; int sb = 255;
    for (; sb > 0; --sb) { if (cum + sup[sb] >= (unsigned)need1) break; cum += sup[sb]; }
    int b = sb * 16 + 15;
    for (; b > sb * 16; --b) { if (cum + hist[b] >= (unsigned)need1) break; cum += hist[b]; }
    s_bin2 = b; s_above += (int)cum;
    s_ocnt = 0; s_ccnt = 0;
  }
  __syncthreads();
  int bin2 = s_bin2;
  int need = NTOP - s_above;
  int* outp = topidx + bh * NTOP;
#pragma unroll
  for (int r = 0; r < 16; ++r) {
    unsigned u = uv[r];
    int b1 = u >> 20, b2 = (u >> 8) & 0xFFF;
    if (b1 > bin1 || (b1 == bin1 && b2 > bin2)) {
      int p = atomicAdd(&s_ocnt, 1);
      outp[p] = t + 256 * r;
    } else if (b1 == bin1 && b2 == bin2) {
      int p = atomicAdd(&s_ccnt, 1);
      if (p < 256) { cand_u[p] = u; cand_i[p] = t + 256 * r; }
    }
  }
  __syncthreads();
  if (t == 0) {
    int cc = s_ccnt < 256 ? s_ccnt : 256;
    int slot = s_ocnt;
    for (int n = 0; n < need; ++n) {
      unsigned bu = 0; int bi = 0x7fffffff, bp = -1;
      for (int c = 0; c < cc; ++c) {
        if (cand_i[c] < 0) continue;
        if (cand_u[c] > bu || (cand_u[c] == bu && cand_i[c] < bi)) {
          bu = cand_u[c]; bi = cand_i[c]; bp = c;
        }
      }
      outp[slot++] = bi;
      cand_i[bp] = -1;
    }
  }
}

// ------------- v row-sum per (b,h) ------------------------------------------
__global__ __launch_bounds__(256) void vsum_partial(
    const float* __restrict__ v, float* __restrict__ part) {
  __shared__ float4 red[256];
  int bh = blockIdx.x, ch = blockIdx.y;
  int t = threadIdx.x;
  int rg = t >> 4, d4 = t & 15;
  const float4* v4 = (const float4*)(v + ((size_t)bh * 4096 + ch * 256) * 64);
  float4 acc = {0.f, 0.f, 0.f, 0.f};
  for (int r = rg; r < 256; r += 16) {
    float4 x = v4[r * 16 + d4];
    acc.x += x.x; acc.y += x.y; acc.z += x.z; acc.w += x.w;
  }
  red[t] = acc;
  __syncthreads();
  for (int s2 = 8; s2 > 0; s2 >>= 1) {
    if (rg < s2) {
      float4 o = red[(rg + s2) * 16 + d4];
      red[t].x += o.x; red[t].y += o.y; red[t].z += o.z; red[t].w += o.w;
    }
    __syncthreads();
  }
  if (rg == 0) ((float4*)part)[((size_t)bh * 16 + ch) * 16 + d4] = red[d4];
}

__global__ __launch_bounds__(64) void vsum_final(
    const float* __restrict__ part, float* __restrict__ vsum) {
  int bh = blockIdx.x, lane = threadIdx.x;
  float acc = 0.f;
  for (int ch = 0; ch < 16; ++ch) acc += part[((size_t)bh * 16 + ch) * 64 + lane];
  vsum[bh * 64 + lane] = acc;
}

// ------------- attention partials: block per (bh, 64-key chunk) -------------
__global__ __launch_bounds__(256) void attn_partial(
    const float* __restrict__ q, const float* __restrict__ k,
    const float* __restrict__ v, const int* __restrict__ topidx,
    float* __restrict__ part_m, float* __restrict__ part_s,
    float* __restrict__ part_o) {
  __shared__ float4 Ks4[64][17];
  __shared__ float4 qs4[36][17];
  __shared__ float S[36][68];
  int bh = blockIdx.y;
  int c = blockIdx.x;
  int l0 = c * 64;
  int t = threadIdx.x;
  size_t base = (size_t)bh * 4096;

  const float4* kg = (const float4*)(k + (base + l0) * 64);
  for (int i = t; i < 64 * 16; i += 256) {
    int row = i >> 4, d4 = i & 15;
    Ks4[row][d4] = kg[row * 16 + d4];
  }
  for (int i = t; i < 36 * 16; i += 256) {
    int u = i >> 4, d4 = i & 15;
    int m = topidx[bh * NTOP + u];
    qs4[u][d4] = ((const float4*)(q + (base + m) * 64))[d4];
  }
  __syncthreads();

  {
    int l = t & 63, ug = t >> 6;
    float acc[9] = {};
#pragma unroll
    for (int d4 = 0; d4 < 16; ++d4) {
      float4 kv = Ks4[l][d4];
#pragma unroll
      for (int j = 0; j < 9; ++j) {
        float4 qv = qs4[ug * 9 + j][d4];
        acc[j] += kv.x * qv.x + kv.y * qv.y + kv.z * qv.z + kv.w * qv.w;
      }
    }
#pragma unroll
    for (int j = 0; j < 9; ++j) S[ug * 9 + j][l] = acc[j] * 0.125f;
  }
  __syncthreads();

  if (t < NTOP) {
    float mx = -INFINITY;
    for (int l = 0; l < 64; ++l) mx = fmaxf(mx, S[t][l]);
    float sm = 0.f;
    for (int l = 0; l < 64; ++l) { float e = expf(S[t][l] - mx); S[t][l] = e; sm += e; }
    part_m[((size_t)bh * NCHUNK + c) * NTOP + t] = mx;
    part_s[((size_t)bh * NCHUNK + c) * NTOP + t] = sm;
  }
  __syncthreads();

  {
    int d = t & 63, ug = t >> 6;
    float pacc[9] = {};
    const float* vg = v + (base + l0) * 64;
    for (int l = 0; l < 64; ++l) {
      float vv = vg[l * 64 + d];
#pragma unroll
      for (int j = 0; j < 9; ++j) pacc[j] += S[ug * 9 + j][l] * vv;
    }
#pragma unroll
    for (int j = 0; j < 9; ++j)
      part_o[(((size_t)bh * NCHUNK + c) * NTOP + ug * 9 + j) * 64 + d] = pacc[j];
  }
}

// ------------- combine partials -> upd --------------------------------------
__global__ __launch_bounds__(256) void attn_combine(
    const float* __restrict__ part_m, const float* __restrict__ part_s,
    const float* __restrict__ part_o, float* __restrict__ upd) {
  __shared__ float wl[4][64];
  int wave = threadIdx.x >> 6;
  int lane = threadIdx.x & 63;
  int widx = blockIdx.x * 4 + wave;  // bh*36 + u
  int bh = widx / NTOP;
  int u = widx % NTOP;
  float m_c = part_m[((size_t)bh * NCHUNK + lane) * NTOP + u];
  float M = m_c;
#pragma unroll
  for (int off = 32; off > 0; off >>= 1) M = fmaxf(M, __shfl_xor(M, off, 64));
  float w = expf(m_c - M);
  float ds = part_s[((size_t)bh * NCHUNK + lane) * NTOP + u] * w;
#pragma unroll
  for (int off = 32; off > 0; off >>= 1) ds += __shfl_xor(ds, off, 64);
  wl[wave][lane] = w;
  __syncthreads();
  float acc = 0.f;
  for (int c2 = 0; c2 < NCHUNK; ++c2)
    acc += part_o[(((size_t)bh * NCHUNK + c2) * NTOP + u) * 64 + lane] * wl[wave][c2];
  upd[(size_t)widx * 64 + lane] = acc / ds;
}

// ------------- output path --------------------------------------------------
__global__ __launch_bounds__(256) void out_base(
    const float* __restrict__ vsum, const float* __restrict__ Wo,
    const float* __restrict__ bo, float* __restrict__ outbase) {
  __shared__ float xb[64];
  int bh = blockIdx.x, c = threadIdx.x;
  if (c < 64) xb[c] = vsum[bh * 64 + c];
  __syncthreads();
  float acc = bo[c];
#pragma unroll 8
  for (int d = 0; d < 64; ++d) {
    float w4 = Wo[d * 256 + c] + Wo[(64 + d) * 256 + c] +
               Wo[(128 + d) * 256 + c] + Wo[(192 + d) * 256 + c];
    acc += xb[d] * w4;
  }
  outbase[bh * 256 + c] = acc;
}

__global__ __launch_bounds__(256) void out_fill(
    const float* __restrict__ outbase, float4* __restrict__ out4) {
  int g = blockIdx.x * 256 + threadIdx.x;   // over 1,048,576 float4
  int c4 = g & 63;
  int bh = g >> 16;                          // row = g>>6; bh = row>>10
  out4[g] = ((const float4*)outbase)[bh * 64 + c4];
}

__global__ __launch_bounds__(256) void out_patch(
    const float* __restrict__ upd, const float* __restrict__ vsum,
    const int* __restrict__ topidx, const float* __restrict__ Wo,
    float* __restrict__ out) {
  __shared__ float dv[64];
  int bhu = blockIdx.x;
  int bh = bhu / NTOP;
  int h = bh & 3, b = bh >> 2;
  int t = threadIdx.x;
  if (t < 64) dv[t] = upd[(size_t)bhu * 64 + t] - vsum[bh * 64 + t];
  __syncthreads();
  int m = topidx[bhu];
  int j = m & 3;
  int lp = h * 1024 + (m >> 2);
  float acc = 0.f;
#pragma unroll 8
  for (int d = 0; d < 64; ++d) acc += dv[d] * Wo[(j * 64 + d) * 256 + t];
  atomicAdd(&out[((size_t)(b * 4096 + lp)) * 256 + t], acc);
}

extern "C" void kernel_launch(void* const* d_in, const int* in_sizes, int n_in,
                              void* d_out, int out_size, void* d_ws, size_t ws_size,
                              hipStream_t stream) {
  const float* et  = (const float*)d_in[0];
  const float* mp  = (const float*)d_in[1];
  const float* co  = (const float*)d_in[2];
  const float* vol = (const float*)d_in[3];
  const float* Wq = (const float*)d_in[4];
  const float* bq = (const float*)d_in[5];
  const float* Wk = (const float*)d_in[6];
  const float* bk = (const float*)d_in[7];
  const float* Wv = (const float*)d_in[8];
  const float* bv = (const float*)d_in[9];
  const float* Wo = (const float*)d_in[10];
  const float* bo = (const float*)d_in[11];
  const int* idxs = (const int*)d_in[12];
  float* out = (float*)d_out;

  char* ws = (char*)d_ws;
  const size_t BIG = 16u * 1024u * 1024u;
  float* qb = (float*)(ws);
  float* kb = (float*)(ws + BIG);
  float* vb = (float*)(ws + 2 * BIG);
  char* sm = ws + 3 * BIG;
  float* Mbuf   = (float*)(sm);                                  // 256 KB
  int*   topidx = (int*)(sm + 262144);                           // pad 4 KB
  float* vpart  = (float*)(sm + 262144 + 4096);                  // 64 KB
  float* vsum   = (float*)(sm + 262144 + 4096 + 65536);          // 4 KB
  char* pm = sm + 262144 + 4096 + 65536 + 4096;
  float* part_m = (float*)(pm);                                  // 144 KB
  float* part_s = (float*)(pm + 147456);                         // 144 KB
  float* part_o = (float*)(pm + 2 * 147456);                     // 9.4 MB
  float* updb   = (float*)(pm + 2 * 147456 + 9437184);           // 144 KB
  float* outbase = (float*)(pm + 2 * 147456 + 9437184 + 147456); // 16 KB
  unsigned short* wt = (unsigned short*)(pm + 2 * 147456 + 9437184 + 147456 + 16384);
  unsigned short* wth0 = wt;                 // 6 x 65536 ushort = 768 KB
  unsigned short* wtl0 = wt + 65536;
  unsigned short* wth1 = wt + 2 * 65536;
  unsigned short* wtl1 = wt + 3 * 65536;
  unsigned short* wth2 = wt + 4 * 65536;
  unsigned short* wtl2 = wt + 5 * 65536;

  // W -> transposed bf16 hi/lo
  wconv<<<dim3(16, 3), 256, 0, stream>>>(Wq, Wk, Wv, wth0, wtl0, wth1, wtl1, wth2, wtl2);

  // fused QKV projection, split-bf16 MFMA
  qkv_mfma<<<dim3(6, 128), 256, 0, stream>>>(
      wth0, wtl0, wth1, wtl1, wth2, wtl2, bq, bk, bv, qb, kb, vb, et, co, mp, vol);

  // sampled scores -> sparsity measure M
  qks_m2<<<dim3(64, BHn), 256, 0, stream>>>(qb, kb, idxs, Mbuf);

  // top-36 per (b,h), radix select
  topk_radix<<<BHn, 256, 0, stream>>>(Mbuf, topidx);

  // v column sums
  vsum_partial<<<dim3(BHn, 16), 256, 0, stream>>>(vb, vpart);
  vsum_final<<<BHn, 64, 0, stream>>>(vpart, vsum);

  // flash-style attention over selected rows
  attn_partial<<<dim3(NCHUNK, BHn), 256, 0, stream>>>(
      qb, kb, vb, topidx, part_m, part_s, part_o);
  attn_combine<<<144, 256, 0, stream>>>(part_m, part_s, part_o, updb);

  // output: per-(b,h) base rows, broadcast fill, sparse rank-update patches
  out_base<<<BHn, 256, 0, stream>>>(vsum, Wo, bo, outbase);
  out_fill<<<4096, 256, 0, stream>>>(outbase, (float4*)out);
  out_patch<<<BHn * NTOP, 256, 0, stream>>>(updb, vsum, topidx, Wo, out);
}

// Round 6
// 151.252 us; speedup vs baseline: 6.8085x; 1.2511x over previous
//
#include <hip/hip_runtime.h>
#include <hip/hip_bf16.h>

// Shapes (fixed): B=4, SEQ=1024, C=256, H=4, Dk=64, L=4096, N_TOP=SAMPLE_K=36
#define BHn 16
#define Ln 4096
#define NTOP 36
#define SKn 36
#define NCHUNK 64   // l-chunks of 64 for attn partials

using s16x8 = __attribute__((ext_vector_type(8))) short;
using u16x8 = __attribute__((ext_vector_type(8))) unsigned short;
using f32x4 = __attribute__((ext_vector_type(4))) float;

__device__ __forceinline__ unsigned short bf_hi(float f) {
  unsigned u = __float_as_uint(f);
  return (unsigned short)((u + 0x7fffu + ((u >> 16) & 1u)) >> 16);
}

// ---------- W[k][n] f32 -> Wt_hi[n][k], Wt_lo[n][k] bf16 (transposed) -------
__global__ __launch_bounds__(256) void wconv(
    const float* __restrict__ W0, const float* __restrict__ W1, const float* __restrict__ W2,
    unsigned short* __restrict__ th0, unsigned short* __restrict__ tl0,
    unsigned short* __restrict__ th1, unsigned short* __restrict__ tl1,
    unsigned short* __restrict__ th2, unsigned short* __restrict__ tl2) {
  int wsel = blockIdx.y;
  const float* W = (wsel == 0) ? W0 : (wsel == 1) ? W1 : W2;
  unsigned short* TH = (wsel == 0) ? th0 : (wsel == 1) ? th1 : th2;
  unsigned short* TL = (wsel == 0) ? tl0 : (wsel == 1) ? tl1 : tl2;
  int kr = blockIdx.x * 16;
  int n = threadIdx.x;
  u16x8 hv[2], lv[2];
#pragma unroll
  for (int j = 0; j < 16; ++j) {
    float f = W[(size_t)(kr + j) * 256 + n];
    unsigned short h = bf_hi(f);
    float lof = f - __uint_as_float(((unsigned)h) << 16);
    hv[j >> 3][j & 7] = h;
    lv[j >> 3][j & 7] = bf_hi(lof);
  }
  *(u16x8*)&TH[(size_t)n * 256 + kr] = hv[0];
  *(u16x8*)&TH[(size_t)n * 256 + kr + 8] = hv[1];
  *(u16x8*)&TL[(size_t)n * 256 + kr] = lv[0];
  *(u16x8*)&TL[(size_t)n * 256 + kr + 8] = lv[1];
}

// ---------- QKV projection: split-bf16 MFMA, 128x128 tile, BK=32 ------------
#define LDW 40
__global__ __launch_bounds__(256, 2) void qkv_mfma(
    const unsigned short* __restrict__ th0, const unsigned short* __restrict__ tl0,
    const unsigned short* __restrict__ th1, const unsigned short* __restrict__ tl1,
    const unsigned short* __restrict__ th2, const unsigned short* __restrict__ tl2,
    const float* __restrict__ b0, const float* __restrict__ b1, const float* __restrict__ b2,
    float* __restrict__ o0, float* __restrict__ o1, float* __restrict__ o2,
    const float* __restrict__ s0, const float* __restrict__ s1,
    const float* __restrict__ s2, const float* __restrict__ s3) {
  __shared__ __align__(16) unsigned short Ah[128 * LDW];
  __shared__ __align__(16) unsigned short Al[128 * LDW];
  __shared__ __align__(16) unsigned short Bh[128 * LDW];
  __shared__ __align__(16) unsigned short Bl[128 * LDW];
  int t = threadIdx.x;
  int wsel = blockIdx.x >> 1;
  int col0 = (blockIdx.x & 1) * 128;
  int row0 = blockIdx.y * 128;
  const unsigned short* TH = (wsel == 0) ? th0 : (wsel == 1) ? th1 : th2;
  const unsigned short* TL = (wsel == 0) ? tl0 : (wsel == 1) ? tl1 : tl2;
  const float* bias = (wsel == 0) ? b0 : (wsel == 1) ? b1 : b2;
  float* O = (wsel == 0) ? o0 : (wsel == 1) ? o1 : o2;

  int srow = t >> 1, half = t & 1;
  int arow = row0 + srow;
  const float* abase;
  {
    int l = arow & 4095, b = arow >> 12;
    int part = (l >> 2) & 3;
    int seq = ((l >> 4) << 2) | (l & 3);
    const float* sp = (part == 0) ? s0 : (part == 1) ? s1 : (part == 2) ? s2 : s3;
    abase = sp + (size_t)((b << 10) + seq) * 256;
  }
  const unsigned short* bh_g = TH + (size_t)(col0 + srow) * 256 + half * 16;
  const unsigned short* bl_g = TL + (size_t)(col0 + srow) * 256 + half * 16;

  int lane = t & 63;
  int wv = t >> 6;
  int wr = wv >> 1, wc = wv & 1;
  int fr = lane & 15, fk = lane >> 4;
  int aoff = (wr * 64 + fr) * LDW + fk * 8;
  int boff = (wc * 64 + fr) * LDW + fk * 8;

  f32x4 acc[4][4] = {};

  for (int k0 = 0; k0 < 256; k0 += 32) {
    const float* ap = abase + k0 + half * 16;
    float4 f0 = ((const float4*)ap)[0];
    float4 f1 = ((const float4*)ap)[1];
    float4 f2 = ((const float4*)ap)[2];
    float4 f3 = ((const float4*)ap)[3];
    float fv[16];
    *(float4*)&fv[0] = f0; *(float4*)&fv[4] = f1;
    *(float4*)&fv[8] = f2; *(float4*)&fv[12] = f3;
    u16x8 hv[2], lv[2];
#pragma unroll
    for (int j = 0; j < 16; ++j) {
      unsigned short h = bf_hi(fv[j]);
      float lof = fv[j] - __uint_as_float(((unsigned)h) << 16);
      hv[j >> 3][j & 7] = h;
      lv[j >> 3][j & 7] = bf_hi(lof);
    }
    int wa = srow * LDW + half * 16;
    *(u16x8*)&Ah[wa] = hv[0]; *(u16x8*)&Ah[wa + 8] = hv[1];
    *(u16x8*)&Al[wa] = lv[0]; *(u16x8*)&Al[wa + 8] = lv[1];
    u16x8 wbh0 = *(const u16x8*)(bh_g + k0);
    u16x8 wbh1 = *(const u16x8*)(bh_g + k0 + 8);
    u16x8 wbl0 = *(const u16x8*)(bl_g + k0);
    u16x8 wbl1 = *(const u16x8*)(bl_g + k0 + 8);
    *(u16x8*)&Bh[wa] = wbh0; *(u16x8*)&Bh[wa + 8] = wbh1;
    *(u16x8*)&Bl[wa] = wbl0; *(u16x8*)&Bl[wa + 8] = wbl1;
    __syncthreads();

    s16x8 fah[4], fal[4], fbh[4], fbl[4];
#pragma unroll
    for (int mi = 0; mi < 4; ++mi) {
      fah[mi] = *(const s16x8*)&Ah[aoff + mi * 16 * LDW];
      fal[mi] = *(const s16x8*)&Al[aoff + mi * 16 * LDW];
    }
#pragma unroll
    for (int ni = 0; ni < 4; ++ni) {
      fbh[ni] = *(const s16x8*)&Bh[boff + ni * 16 * LDW];
      fbl[ni] = *(const s16x8*)&Bl[boff + ni * 16 * LDW];
    }
#pragma unroll
    for (int ni = 0; ni < 4; ++ni) {
#pragma unroll
      for (int mi = 0; mi < 4; ++mi) {
        acc[mi][ni] = __builtin_amdgcn_mfma_f32_16x16x32_bf16(fah[mi], fbh[ni], acc[mi][ni], 0, 0, 0);
        acc[mi][ni] = __builtin_amdgcn_mfma_f32_16x16x32_bf16(fal[mi], fbh[ni], acc[mi][ni], 0, 0, 0);
        acc[mi][ni] = __builtin_amdgcn_mfma_f32_16x16x32_bf16(fah[mi], fbl[ni], acc[mi][ni], 0, 0, 0);
      }
    }
    __syncthreads();
  }

#pragma unroll
  for (int ni = 0; ni < 4; ++ni) {
    int n = col0 + wc * 64 + ni * 16 + fr;
    float bv = bias[n];
#pragma unroll
    for (int mi = 0; mi < 4; ++mi) {
      int mb = row0 + wr * 64 + mi * 16 + fk * 4;
#pragma unroll
      for (int r = 0; r < 4; ++r)
        O[(size_t)(mb + r) * 256 + n] = acc[mi][ni][r] + bv;
    }
  }
}

// ------------- sampled QK^T and M, XCD-pinned: each XCD owns 2 bh -----------
// Per-XCD working set = 2 x (K 1MB + Q 1MB) = 4MB = L2 capacity; the random
// K-row gather then hits XCD-local L2 instead of L3/HBM.
__global__ __launch_bounds__(256) void qks_m3(
    const float* __restrict__ q, const float* __restrict__ k,
    const int* __restrict__ idxs, float* __restrict__ Mout) {
  __shared__ float qs[64][68];
  __shared__ int il[64 * SKn];
  int g = blockIdx.x;             // 0..1023
  int x = g & 7;                  // XCD (hw round-robin on flat id)
  int i = g >> 3;                 // 0..127
  int bh = (x << 1) | (i >> 6);   // 2 bh per XCD
  int s0 = (i & 63) * 64;
  int t = threadIdx.x;
  size_t base = (size_t)bh << 12;
  for (int i2 = t; i2 < 1024; i2 += 256) {
    int row = i2 >> 4, d4 = i2 & 15;
    *(float4*)&qs[row][d4 * 4] = ((const float4*)(q + (base + s0 + row) * 64))[d4];
  }
  for (int i2 = t; i2 < 64 * SKn; i2 += 256) il[i2] = idxs[s0 * SKn + i2];
  __syncthreads();
  int sl = t >> 2;
  int dq = t & 3;
  float qr[16];
#pragma unroll
  for (int i2 = 0; i2 < 4; ++i2)
    *(float4*)&qr[i2 * 4] = *(const float4*)&qs[sl][i2 * 16 + dq * 4];
  float mx = -INFINITY, sm = 0.f;
  const float4* kb4 = (const float4*)(k + base * 64);
#pragma unroll 4
  for (int j = 0; j < SKn; ++j) {
    int l = il[sl * SKn + j];
    const float4* kr = kb4 + (size_t)l * 16;
    float acc = 0.f;
#pragma unroll
    for (int i2 = 0; i2 < 4; ++i2) {
      float4 kv = kr[i2 * 4 + dq];
      acc += kv.x * qr[i2 * 4] + kv.y * qr[i2 * 4 + 1] + kv.z * qr[i2 * 4 + 2] + kv.w * qr[i2 * 4 + 3];
    }
    acc += __shfl_xor(acc, 1, 64);
    acc += __shfl_xor(acc, 2, 64);
    mx = fmaxf(mx, acc);
    sm += acc;
  }
  if (dq == 0) Mout[base + s0 + sl] = mx - sm * (1.0f / 4096.0f);
}

// ------------- top-36 per (b,h): two-phase radix select ---------------------
__global__ __launch_bounds__(256) void topk_radix(
    const float* __restrict__ M, int* __restrict__ topidx) {
  __shared__ unsigned hist[4096];
  __shared__ unsigned sup[256];
  __shared__ unsigned cand_u[256];
  __shared__ int cand_i[256];
  __shared__ int s_bin1, s_bin2, s_above, s_ocnt, s_ccnt;
  int bh = blockIdx.x;
  int t = threadIdx.x;
  int mbase = bh * 4096;
  unsigned uv[16];
  for (int i = t; i < 4096; i += 256) hist[i] = 0;
  __syncthreads();
#pragma unroll
  for (int r = 0; r < 16; ++r) {
    unsigned b = __float_as_uint(M[mbase + t + 256 * r]);
    unsigned u = b ^ ((unsigned)((int)b >> 31) | 0x80000000u);
    uv[r] = u;
    atomicAdd(&hist[u >> 20], 1u);
  }
  __syncthreads();
  {
    unsigned ssum = 0;
    for (int i = 0; i < 16; ++i) ssum += hist[t * 16 + i];
    sup[t] = ssum;
  }
  __syncthreads();
  if (t == 0) {
    unsigned cum = 0; int sb = 255;
    for (; sb > 0; --sb) { if (cum + sup[sb] >= NTOP) break; cum += sup[sb]; }
    int b = sb * 16 + 15;
    for (; b > sb * 16; --b) { if (cum + hist[b] >= NTOP) break; cum += hist[b]; }
    s_bin1 = b; s_above = (int)cum;
  }
  __syncthreads();
  int bin1 = s_bin1;
  int need1 = NTOP - s_above;
  __syncthreads();
  for (int i = t; i < 4096; i += 256) hist[i] = 0;
  __syncthreads();
#pragma unroll
  for (int r = 0; r < 16; ++r)
    if ((int)(uv[r] >> 20) == bin1) atomicAdd(&hist[(uv[r] >> 8) & 0xFFF], 1u);
  __syncthreads();
  {
    unsigned ssum = 0;
    for (int i = 0; i < 16; ++i) ssum += hist[t * 16 + i];
    sup[t] = ssum;
  }
  __syncthreads();
  if (t == 0) {
    unsigned cum = 0; int sb = 255;
    for (; sb > 0; --sb) { if (cum + sup[sb] >= (unsigned)need1) break; cum += sup[sb]; }
    int b = sb * 16 + 15;
    for (; b > sb * 16; --b) { if (cum + hist[b] >= (unsigned)need1) break; cum += hist[b]; }
    s_bin2 = b; s_above += (int)cum;
    s_ocnt = 0; s_ccnt = 0;
  }
  __syncthreads();
  int bin2 = s_bin2;
  int need = NTOP - s_above;
  int* outp = topidx + bh * NTOP;
#pragma unroll
  for (int r = 0; r < 16; ++r) {
    unsigned u = uv[r];
    int b1 = u >> 20, b2 = (u >> 8) & 0xFFF;
    if (b1 > bin1 || (b1 == bin1 && b2 > bin2)) {
      int p = atomicAdd(&s_ocnt, 1);
      outp[p] = t + 256 * r;
    } else if (b1 == bin1 && b2 == bin2) {
      int p = atomicAdd(&s_ccnt, 1);
      if (p < 256) { cand_u[p] = u; cand_i[p] = t + 256 * r; }
    }
  }
  __syncthreads();
  if (t == 0) {
    int cc = s_ccnt < 256 ? s_ccnt : 256;
    int slot = s_ocnt;
    for (int n = 0; n < need; ++n) {
      unsigned bu = 0; int bi = 0x7fffffff, bp = -1;
      for (int c = 0; c < cc; ++c) {
        if (cand_i[c] < 0) continue;
        if (cand_u[c] > bu || (cand_u[c] == bu && cand_i[c] < bi)) {
          bu = cand_u[c]; bi = cand_i[c]; bp = c;
        }
      }
      outp[slot++] = bi;
      cand_i[bp] = -1;
    }
  }
}

// ------------- v row-sum per (b,h) ------------------------------------------
__global__ __launch_bounds__(256) void vsum_partial(
    const float* __restrict__ v, float* __restrict__ part) {
  __shared__ float4 red[256];
  int bh = blockIdx.x, ch = blockIdx.y;
  int t = threadIdx.x;
  int rg = t >> 4, d4 = t & 15;
  const float4* v4 = (const float4*)(v + ((size_t)bh * 4096 + ch * 256) * 64);
  float4 acc = {0.f, 0.f, 0.f, 0.f};
  for (int r = rg; r < 256; r += 16) {
    float4 x = v4[r * 16 + d4];
    acc.x += x.x; acc.y += x.y; acc.z += x.z; acc.w += x.w;
  }
  red[t] = acc;
  __syncthreads();
  for (int s2 = 8; s2 > 0; s2 >>= 1) {
    if (rg < s2) {
      float4 o = red[(rg + s2) * 16 + d4];
      red[t].x += o.x; red[t].y += o.y; red[t].z += o.z; red[t].w += o.w;
    }
    __syncthreads();
  }
  if (rg == 0) ((float4*)part)[((size_t)bh * 16 + ch) * 16 + d4] = red[d4];
}

__global__ __launch_bounds__(64) void vsum_final(
    const float* __restrict__ part, float* __restrict__ vsum) {
  int bh = blockIdx.x, lane = threadIdx.x;
  float acc = 0.f;
  for (int ch = 0; ch < 16; ++ch) acc += part[((size_t)bh * 16 + ch) * 64 + lane];
  vsum[bh * 64 + lane] = acc;
}

// ------------- attention partials: block per (bh, 64-key chunk) -------------
__global__ __launch_bounds__(256) void attn_partial(
    const float* __restrict__ q, const float* __restrict__ k,
    const float* __restrict__ v, const int* __restrict__ topidx,
    float* __restrict__ part_m, float* __restrict__ part_s,
    float* __restrict__ part_o) {
  __shared__ float4 Ks4[64][17];
  __shared__ float4 qs4[36][17];
  __shared__ float S[36][68];
  int bh = blockIdx.y;
  int c = blockIdx.x;
  int l0 = c * 64;
  int t = threadIdx.x;
  size_t base = (size_t)bh * 4096;

  const float4* kg = (const float4*)(k + (base + l0) * 64);
  for (int i = t; i < 64 * 16; i += 256) {
    int row = i >> 4, d4 = i & 15;
    Ks4[row][d4] = kg[row * 16 + d4];
  }
  for (int i = t; i < 36 * 16; i += 256) {
    int u = i >> 4, d4 = i & 15;
    int m = topidx[bh * NTOP + u];
    qs4[u][d4] = ((const float4*)(q + (base + m) * 64))[d4];
  }
  __syncthreads();

  {
    int l = t & 63, ug = t >> 6;
    float acc[9] = {};
#pragma unroll
    for (int d4 = 0; d4 < 16; ++d4) {
      float4 kv = Ks4[l][d4];
#pragma unroll
      for (int j = 0; j < 9; ++j) {
        float4 qv = qs4[ug * 9 + j][d4];
        acc[j] += kv.x * qv.x + kv.y * qv.y + kv.z * qv.z + kv.w * qv.w;
      }
    }
#pragma unroll
    for (int j = 0; j < 9; ++j) S[ug * 9 + j][l] = acc[j] * 0.125f;
  }
  __syncthreads();

  if (t < NTOP) {
    float mx = -INFINITY;
    for (int l = 0; l < 64; ++l) mx = fmaxf(mx, S[t][l]);
    float sm = 0.f;
    for (int l = 0; l < 64; ++l) { float e = expf(S[t][l] - mx); S[t][l] = e; sm += e; }
    part_m[((size_t)bh * NCHUNK + c) * NTOP + t] = mx;
    part_s[((size_t)bh * NCHUNK + c) * NTOP + t] = sm;
  }
  __syncthreads();

  {
    int d = t & 63, ug = t >> 6;
    float pacc[9] = {};
    const float* vg = v + (base + l0) * 64;
    for (int l = 0; l < 64; ++l) {
      float vv = vg[l * 64 + d];
#pragma unroll
      for (int j = 0; j < 9; ++j) pacc[j] += S[ug * 9 + j][l] * vv;
    }
#pragma unroll
    for (int j = 0; j < 9; ++j)
      part_o[(((size_t)bh * NCHUNK + c) * NTOP + ug * 9 + j) * 64 + d] = pacc[j];
  }
}

// ------------- combine partials -> upd --------------------------------------
__global__ __launch_bounds__(256) void attn_combine(
    const float* __restrict__ part_m, const float* __restrict__ part_s,
    const float* __restrict__ part_o, float* __restrict__ upd) {
  __shared__ float wl[4][64];
  int wave = threadIdx.x >> 6;
  int lane = threadIdx.x & 63;
  int widx = blockIdx.x * 4 + wave;  // bh*36 + u
  int bh = widx / NTOP;
  int u = widx % NTOP;
  float m_c = part_m[((size_t)bh * NCHUNK + lane) * NTOP + u];
  float M = m_c;
#pragma unroll
  for (int off = 32; off > 0; off >>= 1) M = fmaxf(M, __shfl_xor(M, off, 64));
  float w = expf(m_c - M);
  float ds = part_s[((size_t)bh * NCHUNK + lane) * NTOP + u] * w;
#pragma unroll
  for (int off = 32; off > 0; off >>= 1) ds += __shfl_xor(ds, off, 64);
  wl[wave][lane] = w;
  __syncthreads();
  float acc = 0.f;
  for (int c2 = 0; c2 < NCHUNK; ++c2)
    acc += part_o[(((size_t)bh * NCHUNK + c2) * NTOP + u) * 64 + lane] * wl[wave][c2];
  upd[(size_t)widx * 64 + lane] = acc / ds;
}

// ------------- output path --------------------------------------------------
__global__ __launch_bounds__(256) void out_base(
    const float* __restrict__ vsum, const float* __restrict__ Wo,
    const float* __restrict__ bo, float* __restrict__ outbase) {
  __shared__ float xb[64];
  int bh = blockIdx.x, c = threadIdx.x;
  if (c < 64) xb[c] = vsum[bh * 64 + c];
  __syncthreads();
  float acc = bo[c];
#pragma unroll 8
  for (int d = 0; d < 64; ++d) {
    float w4 = Wo[d * 256 + c] + Wo[(64 + d) * 256 + c] +
               Wo[(128 + d) * 256 + c] + Wo[(192 + d) * 256 + c];
    acc += xb[d] * w4;
  }
  outbase[bh * 256 + c] = acc;
}

__global__ __launch_bounds__(256) void out_fill(
    const float* __restrict__ outbase, float4* __restrict__ out4) {
  int g = blockIdx.x * 256 + threadIdx.x;
  int c4 = g & 63;
  int bh = g >> 16;
  out4[g] = ((const float4*)outbase)[bh * 64 + c4];
}

__global__ __launch_bounds__(256) void out_patch(
    const float* __restrict__ upd, const float* __restrict__ vsum,
    const int* __restrict__ topidx, const float* __restrict__ Wo,
    float* __restrict__ out) {
  __shared__ float dv[64];
  int bhu = blockIdx.x;
  int bh = bhu / NTOP;
  int h = bh & 3, b = bh >> 2;
  int t = threadIdx.x;
  if (t < 64) dv[t] = upd[(size_t)bhu * 64 + t] - vsum[bh * 64 + t];
  __syncthreads();
  int m = topidx[bhu];
  int j = m & 3;
  int lp = h * 1024 + (m >> 2);
  float acc = 0.f;
#pragma unroll 8
  for (int d = 0; d < 64; ++d) acc += dv[d] * Wo[(j * 64 + d) * 256 + t];
  atomicAdd(&out[((size_t)(b * 4096 + lp)) * 256 + t], acc);
}

extern "C" void kernel_launch(void* const* d_in, const int* in_sizes, int n_in,
                              void* d_out, int out_size, void* d_ws, size_t ws_size,
                              hipStream_t stream) {
  const float* et  = (const float*)d_in[0];
  const float* mp  = (const float*)d_in[1];
  const float* co  = (const float*)d_in[2];
  const float* vol = (const float*)d_in[3];
  const float* Wq = (const float*)d_in[4];
  const float* bq = (const float*)d_in[5];
  const float* Wk = (const float*)d_in[6];
  const float* bk = (const float*)d_in[7];
  const float* Wv = (const float*)d_in[8];
  const float* bv = (const float*)d_in[9];
  const float* Wo = (const float*)d_in[10];
  const float* bo = (const float*)d_in[11];
  const int* idxs = (const int*)d_in[12];
  float* out = (float*)d_out;

  char* ws = (char*)d_ws;
  const size_t BIG = 16u * 1024u * 1024u;
  float* qb = (float*)(ws);
  float* kb = (float*)(ws + BIG);
  float* vb = (float*)(ws + 2 * BIG);
  char* sm = ws + 3 * BIG;
  float* Mbuf   = (float*)(sm);                                  // 256 KB
  int*   topidx = (int*)(sm + 262144);                           // pad 4 KB
  float* vpart  = (float*)(sm + 262144 + 4096);                  // 64 KB
  float* vsum   = (float*)(sm + 262144 + 4096 + 65536);          // 4 KB
  char* pm = sm + 262144 + 4096 + 65536 + 4096;
  float* part_m = (float*)(pm);                                  // 144 KB
  float* part_s = (float*)(pm + 147456);                         // 144 KB
  float* part_o = (float*)(pm + 2 * 147456);                     // 9.4 MB
  float* updb   = (float*)(pm + 2 * 147456 + 9437184);           // 144 KB
  float* outbase = (float*)(pm + 2 * 147456 + 9437184 + 147456); // 16 KB
  unsigned short* wt = (unsigned short*)(pm + 2 * 147456 + 9437184 + 147456 + 16384);
  unsigned short* wth0 = wt;
  unsigned short* wtl0 = wt + 65536;
  unsigned short* wth1 = wt + 2 * 65536;
  unsigned short* wtl1 = wt + 3 * 65536;
  unsigned short* wth2 = wt + 4 * 65536;
  unsigned short* wtl2 = wt + 5 * 65536;

  // W -> transposed bf16 hi/lo
  wconv<<<dim3(16, 3), 256, 0, stream>>>(Wq, Wk, Wv, wth0, wtl0, wth1, wtl1, wth2, wtl2);

  // fused QKV projection, split-bf16 MFMA
  qkv_mfma<<<dim3(6, 128), 256, 0, stream>>>(
      wth0, wtl0, wth1, wtl1, wth2, wtl2, bq, bk, bv, qb, kb, vb, et, co, mp, vol);

  // sampled scores -> sparsity measure M (XCD-pinned gather)
  qks_m3<<<1024, 256, 0, stream>>>(qb, kb, idxs, Mbuf);

  // top-36 per (b,h), radix select
  topk_radix<<<BHn, 256, 0, stream>>>(Mbuf, topidx);

  // v column sums
  vsum_partial<<<dim3(BHn, 16), 256, 0, stream>>>(vb, vpart);
  vsum_final<<<BHn, 64, 0, stream>>>(vpart, vsum);

  // flash-style attention over selected rows
  attn_partial<<<dim3(NCHUNK, BHn), 256, 0, stream>>>(
      qb, kb, vb, topidx, part_m, part_s, part_o);
  attn_combine<<<144, 256, 0, stream>>>(part_m, part_s, part_o, updb);

  // output: per-(b,h) base rows, broadcast fill, sparse rank-update patches
  out_base<<<BHn, 256, 0, stream>>>(vsum, Wo, bo, outbase);
  out_fill<<<4096, 256, 0, stream>>>(outbase, (float4*)out);
  out_patch<<<BHn * NTOP, 256, 0, stream>>>(updb, vsum, topidx, Wo, out);
}